// Round 1
// baseline (1745.303 us; speedup 1.0000x reference)
//
#include <hip/hip_runtime.h>
#include <hip/hip_bf16.h>

#define N_PAPER 100000
#define N_LABEL 128
#define E_CITES 1600000
#define E_IS    100000

// ---------------- CSR build ----------------
__global__ __launch_bounds__(256) void count_edges(
    const int* __restrict__ cd, const int* __restrict__ iss,
    int* __restrict__ cnt_c, int* __restrict__ cnt_r)
{
    int i = blockIdx.x * 256 + threadIdx.x;
    if (i < E_CITES) {
        atomicAdd(&cnt_c[cd[i]], 1);
    } else if (i < E_CITES + E_IS) {
        atomicAdd(&cnt_r[iss[i - E_CITES]], 1);
    }
}

__device__ void scan_one(const int* __restrict__ cnt, int* __restrict__ rp,
                         int* __restrict__ cur, float* __restrict__ dinv, int n)
{
    const int T = 1024;
    __shared__ int sums[T];
    int t = threadIdx.x;
    int chunk = (n + T - 1) / T;
    int beg = t * chunk;
    int end = min(beg + chunk, n);
    int s = 0;
    for (int i = beg; i < end; ++i) s += cnt[i];
    sums[t] = s;
    __syncthreads();
    for (int off = 1; off < T; off <<= 1) {
        int v = (t >= off) ? sums[t - off] : 0;
        __syncthreads();
        sums[t] += v;
        __syncthreads();
    }
    int run = (t == 0) ? 0 : sums[t - 1];   // exclusive prefix
    for (int i = beg; i < end; ++i) {
        rp[i] = run; cur[i] = run;
        if (dinv) dinv[i] = rsqrtf((float)cnt[i] + 1.0f);
        run += cnt[i];
    }
    if (t == T - 1) rp[n] = sums[T - 1];
}

__global__ __launch_bounds__(1024) void scan_build(
    const int* cnt_c, int* rp_c, int* cur_c, float* dinv,
    const int* cnt_r, int* rp_r, int* cur_r)
{
    scan_one(cnt_c, rp_c, cur_c, dinv, N_PAPER);
    __syncthreads();
    scan_one(cnt_r, rp_r, cur_r, nullptr, N_PAPER);
}

__global__ __launch_bounds__(256) void scatter_edges(
    const int* __restrict__ cs, const int* __restrict__ cd,
    const int* __restrict__ iss, const int* __restrict__ isd,
    int* __restrict__ cur_c, int* __restrict__ col_c,
    int* __restrict__ cur_r, int* __restrict__ col_r)
{
    int i = blockIdx.x * 256 + threadIdx.x;
    if (i < E_CITES) {
        int pos = atomicAdd(&cur_c[cd[i]], 1);
        col_c[pos] = cs[i];
    } else if (i < E_CITES + E_IS) {
        int e = i - E_CITES;
        int pos = atomicAdd(&cur_r[iss[e]], 1);
        col_r[pos] = isd[e];
    }
}

// ---------------- weight packing ----------------
// W1cat [128 x 256] = [l1_gcn_W | l1_rev_rootW]; W2cat [128 x 128] = [l2_gcn_W | l2_rev_rootW]
__global__ __launch_bounds__(256) void pack_w(
    const float* __restrict__ g1, const float* __restrict__ r1, float* __restrict__ W1cat,
    const float* __restrict__ g2, const float* __restrict__ r2, float* __restrict__ W2cat)
{
    int i = blockIdx.x * 256 + threadIdx.x;
    if (i < 128 * 256) {
        int k = i >> 8, j = i & 255;
        W1cat[i] = (j < 128) ? g1[k * 128 + j] : r1[k * 128 + (j - 128)];
    }
    if (i < 128 * 128) {
        int k = i >> 7, j = i & 127;
        W2cat[i] = (j < 64) ? g2[k * 64 + j] : r2[k * 64 + (j - 64)];
    }
}

// ---------------- tiny GEMM: out[M x N] = X[M x 128] @ W[128 x N], grid=M blocks ----------------
__global__ __launch_bounds__(128) void small_mm(
    const float* __restrict__ X, const float* __restrict__ W,
    float* __restrict__ out, int N)
{
    __shared__ float xrow[128];
    int l = blockIdx.x, t = threadIdx.x;
    xrow[t] = X[(size_t)l * 128 + t];
    __syncthreads();
    if (t < N) {
        float o = 0.f;
        for (int k = 0; k < 128; ++k) o = fmaf(xrow[k], W[k * N + t], o);
        out[(size_t)l * N + t] = o;
    }
}

// ---------------- main GEMM: C[M x N] = A[M x 128] @ W[128 x N] (fp32 tiled) ----------------
__global__ __launch_bounds__(256) void gemm_f32(
    const float* __restrict__ A, const float* __restrict__ W,
    float* __restrict__ C, int M, int N)
{
    __shared__ float As[16][64];   // [k][m]
    __shared__ float Ws[16][64];   // [k][n]
    int tid = threadIdx.x;
    int tx = tid & 15, ty = tid >> 4;
    int m0 = blockIdx.x * 64, n0 = blockIdx.y * 64;
    float acc[4][4] = {};
    int lr = tid >> 2;            // A-tile row 0..63
    int lc = (tid & 3) * 4;       // A-tile k offset 0,4,8,12
    int wk = tid >> 4;            // W-tile k 0..15
    int wn = (tid & 15) * 4;      // W-tile n offset
    for (int k0 = 0; k0 < 128; k0 += 16) {
        int gm = m0 + lr;
        float4 va = make_float4(0.f, 0.f, 0.f, 0.f);
        if (gm < M) va = *(const float4*)(A + (size_t)gm * 128 + k0 + lc);
        As[lc + 0][lr] = va.x; As[lc + 1][lr] = va.y;
        As[lc + 2][lr] = va.z; As[lc + 3][lr] = va.w;
        *(float4*)&Ws[wk][wn] = *(const float4*)(W + (size_t)(k0 + wk) * N + n0 + wn);
        __syncthreads();
        #pragma unroll
        for (int kk = 0; kk < 16; ++kk) {
            float a[4], b[4];
            *(float4*)a = *(const float4*)&As[kk][ty * 4];
            *(float4*)b = *(const float4*)&Ws[kk][tx * 4];
            #pragma unroll
            for (int i = 0; i < 4; ++i)
                #pragma unroll
                for (int j = 0; j < 4; ++j)
                    acc[i][j] = fmaf(a[i], b[j], acc[i][j]);
        }
        __syncthreads();
    }
    #pragma unroll
    for (int i = 0; i < 4; ++i) {
        int gm = m0 + ty * 4 + i;
        if (gm < M)
            *(float4*)(C + (size_t)gm * N + n0 + tx * 4) =
                make_float4(acc[i][0], acc[i][1], acc[i][2], acc[i][3]);
    }
}

// ---------------- fused paper-side assembly ----------------
// out = [relu] 0.5 * ( dinv_i * sum_e dinv[src]*Hg[src] + dinv_i^2 * Hg_i + gcn_b
//                     + Hr_i + sum_{is e} yrev[lab] + rev_relb )
// H is [M x 2D] with Hg = cols [0,D), Hr = cols [D,2D). One wave per node.
template<int D, bool RELU>
__global__ __launch_bounds__(256) void paper_assemble(
    const float* __restrict__ H,
    const int* __restrict__ rp_c, const int* __restrict__ col_c,
    const float* __restrict__ dinv,
    const int* __restrict__ rp_r, const int* __restrict__ col_r,
    const float* __restrict__ yrev,
    const float* __restrict__ gcn_b, const float* __restrict__ rev_relb,
    float* __restrict__ out)
{
    const int NV = D / 64;
    int w = (int)((blockIdx.x * 256 + threadIdx.x) >> 6);  // node id (uniform per wave)
    if (w >= N_PAPER) return;
    int lane = threadIdx.x & 63;
    float acc[NV];
    #pragma unroll
    for (int v = 0; v < NV; ++v) acc[v] = 0.f;
    int s = rp_c[w], e = rp_c[w + 1];
    for (int j = s; j < e; ++j) {
        int src = col_c[j];
        float sc = dinv[src];
        const float* hg = H + (size_t)src * (2 * D);
        #pragma unroll
        for (int v = 0; v < NV; ++v) acc[v] = fmaf(sc, hg[lane + v * 64], acc[v]);
    }
    float di = dinv[w];
    const float* hrow = H + (size_t)w * (2 * D);
    float res[NV];
    #pragma unroll
    for (int v = 0; v < NV; ++v) {
        int d = lane + v * 64;
        res[v] = di * acc[v] + di * di * hrow[d] + hrow[D + d] + gcn_b[d] + rev_relb[d];
    }
    int s2 = rp_r[w], e2 = rp_r[w + 1];
    for (int j = s2; j < e2; ++j) {
        int lab = col_r[j];
        const float* yr = yrev + (size_t)lab * D;
        #pragma unroll
        for (int v = 0; v < NV; ++v) res[v] += yr[lane + v * 64];
    }
    #pragma unroll
    for (int v = 0; v < NV; ++v) {
        float o = 0.5f * res[v];
        if (RELU) o = fmaxf(o, 0.f);
        out[(size_t)w * D + lane + v * 64] = o;
    }
}

// ---------------- label-side: aggregate 100K edges onto 128 labels + tiny GEMM ----------------
// out[l] = [relu]( aggL[l] @ relW + Xdst[l] @ rootW + relb ),  aggL[l] = sum_{isd[e]==l} Xsrc[iss[e]]
template<int DOUT, bool RELU>
__global__ __launch_bounds__(128) void label_kernel(
    const float* __restrict__ Xsrc, const float* __restrict__ Xdst,
    const int* __restrict__ iss, const int* __restrict__ isd,
    const float* __restrict__ relW, const float* __restrict__ rootW,
    const float* __restrict__ relb, float* __restrict__ out)
{
    const int CH = 4096;
    __shared__ int list[CH];
    __shared__ int cnt;
    __shared__ float arow[128];
    __shared__ float xrow[128];
    int l = blockIdx.x, t = threadIdx.x;
    float acc = 0.f;   // aggL[l][t], t = feature dim
    for (int base = 0; base < E_IS; base += CH) {
        if (t == 0) cnt = 0;
        __syncthreads();
        int nE = min(CH, E_IS - base);
        for (int e = t; e < nE; e += 128) {
            if (isd[base + e] == l) {
                int p = atomicAdd(&cnt, 1);
                list[p] = iss[base + e];
            }
        }
        __syncthreads();
        int c = cnt;
        for (int m = 0; m < c; ++m)
            acc += Xsrc[(size_t)list[m] * 128 + t];
        __syncthreads();
    }
    arow[t] = acc;
    xrow[t] = Xdst[(size_t)l * 128 + t];
    __syncthreads();
    if (t < DOUT) {
        float o = relb[t];
        for (int k = 0; k < 128; ++k)
            o = fmaf(arow[k], relW[k * DOUT + t], fmaf(xrow[k], rootW[k * DOUT + t], o));
        if (RELU) o = fmaxf(o, 0.f);
        out[(size_t)l * DOUT + t] = o;
    }
}

extern "C" void kernel_launch(void* const* d_in, const int* in_sizes, int n_in,
                              void* d_out, int out_size, void* d_ws, size_t ws_size,
                              hipStream_t stream)
{
    const float* xp          = (const float*)d_in[0];
    const float* xl          = (const float*)d_in[1];
    const int*   cs          = (const int*)d_in[2];
    const int*   cd          = (const int*)d_in[3];
    const int*   iss         = (const int*)d_in[4];
    const int*   isd         = (const int*)d_in[5];
    const float* l1_gcn_W    = (const float*)d_in[6];
    const float* l1_gcn_b    = (const float*)d_in[7];
    const float* l1_is_relW  = (const float*)d_in[8];
    const float* l1_is_relb  = (const float*)d_in[9];
    const float* l1_is_rootW = (const float*)d_in[10];
    const float* l1_rev_relW = (const float*)d_in[11];
    const float* l1_rev_relb = (const float*)d_in[12];
    const float* l1_rev_rootW= (const float*)d_in[13];
    const float* l2_gcn_W    = (const float*)d_in[14];
    const float* l2_gcn_b    = (const float*)d_in[15];
    const float* l2_is_relW  = (const float*)d_in[16];
    const float* l2_is_relb  = (const float*)d_in[17];
    const float* l2_is_rootW = (const float*)d_in[18];
    const float* l2_rev_relW = (const float*)d_in[19];
    const float* l2_rev_relb = (const float*)d_in[20];
    const float* l2_rev_rootW= (const float*)d_in[21];

    char* ws = (char*)d_ws;
    size_t off = 0;
    auto alloc = [&](size_t bytes) {
        char* p = ws + off;
        off += (bytes + 255) & ~(size_t)255;
        return p;
    };
    float* H     = (float*)alloc((size_t)N_PAPER * 256 * 4);  // H1 [100K x 256]; reused as H2 [100K x 128]
    float* hp1   = (float*)alloc((size_t)N_PAPER * 128 * 4);
    int*   col_c = (int*)alloc((size_t)E_CITES * 4);
    int*   col_r = (int*)alloc((size_t)E_IS * 4);
    int*   rp_c  = (int*)alloc((size_t)(N_PAPER + 1) * 4);
    int*   cur_c = (int*)alloc((size_t)(N_PAPER + 1) * 4);
    int*   rp_r  = (int*)alloc((size_t)(N_PAPER + 1) * 4);
    int*   cur_r = (int*)alloc((size_t)(N_PAPER + 1) * 4);
    int*   cnt_c = (int*)alloc((size_t)N_PAPER * 4);
    int*   cnt_r = (int*)alloc((size_t)N_PAPER * 4);
    float* dinv  = (float*)alloc((size_t)N_PAPER * 4);
    float* W1cat = (float*)alloc(128 * 256 * 4);
    float* W2cat = (float*)alloc(128 * 128 * 4);
    float* yrev1 = (float*)alloc(128 * 128 * 4);
    float* yrev2 = (float*)alloc(128 * 64 * 4);
    float* hl1   = (float*)alloc(128 * 128 * 4);

    float* zp = (float*)d_out;                          // [100000 x 64]
    float* zl = (float*)d_out + (size_t)N_PAPER * 64;   // [128 x 64]

    hipMemsetAsync(cnt_c, 0, (size_t)N_PAPER * 4, stream);
    hipMemsetAsync(cnt_r, 0, (size_t)N_PAPER * 4, stream);

    int eTot = E_CITES + E_IS;
    count_edges<<<(eTot + 255) / 256, 256, 0, stream>>>(cd, iss, cnt_c, cnt_r);
    scan_build<<<1, 1024, 0, stream>>>(cnt_c, rp_c, cur_c, dinv, cnt_r, rp_r, cur_r);
    scatter_edges<<<(eTot + 255) / 256, 256, 0, stream>>>(cs, cd, iss, isd,
                                                          cur_c, col_c, cur_r, col_r);
    pack_w<<<128, 256, 0, stream>>>(l1_gcn_W, l1_rev_rootW, W1cat, l2_gcn_W, l2_rev_rootW, W2cat);
    small_mm<<<128, 128, 0, stream>>>(xl, l1_rev_relW, yrev1, 128);

    // ---- layer 1 ----
    dim3 g1((N_PAPER + 63) / 64, 256 / 64);
    gemm_f32<<<g1, 256, 0, stream>>>(xp, W1cat, H, N_PAPER, 256);
    paper_assemble<128, true><<<(N_PAPER + 3) / 4, 256, 0, stream>>>(
        H, rp_c, col_c, dinv, rp_r, col_r, yrev1, l1_gcn_b, l1_rev_relb, hp1);
    label_kernel<128, true><<<N_LABEL, 128, 0, stream>>>(
        xp, xl, iss, isd, l1_is_relW, l1_is_rootW, l1_is_relb, hl1);
    small_mm<<<128, 128, 0, stream>>>(hl1, l2_rev_relW, yrev2, 64);

    // ---- layer 2 ----
    dim3 g2((N_PAPER + 63) / 64, 128 / 64);
    gemm_f32<<<g2, 256, 0, stream>>>(hp1, W2cat, H, N_PAPER, 128);
    paper_assemble<64, false><<<(N_PAPER + 3) / 4, 256, 0, stream>>>(
        H, rp_c, col_c, dinv, rp_r, col_r, yrev2, l2_gcn_b, l2_rev_relb, zp);
    label_kernel<64, false><<<N_LABEL, 128, 0, stream>>>(
        hp1, hl1, iss, isd, l2_is_relW, l2_is_rootW, l2_is_relb, zl);
}

// Round 2
// 1156.004 us; speedup vs baseline: 1.5098x; 1.5098x over previous
//
#include <hip/hip_runtime.h>
#include <hip/hip_bf16.h>

#define N_PAPER 100000
#define N_LABEL 128
#define E_CITES 1600000
#define E_IS    100000
#define SCAN_B  98   // ceil(100000/1024)

typedef __bf16 bf16x8 __attribute__((ext_vector_type(8)));
typedef float  f32x4  __attribute__((ext_vector_type(4)));

static __device__ __forceinline__ float bf_lo(unsigned u) {
    union { unsigned u; float f; } v; v.u = u << 16; return v.f;
}
static __device__ __forceinline__ float bf_hi(unsigned u) {
    union { unsigned u; float f; } v; v.u = u & 0xffff0000u; return v.f;
}

// ---------------- CSR build ----------------
__global__ __launch_bounds__(256) void count_edges(
    const int* __restrict__ cd, const int* __restrict__ iss,
    int* __restrict__ cnt_c, int* __restrict__ cnt_r)
{
    int i = blockIdx.x * 256 + threadIdx.x;
    if (i < E_CITES) {
        atomicAdd(&cnt_c[cd[i]], 1);
    } else if (i < E_CITES + E_IS) {
        atomicAdd(&cnt_r[iss[i - E_CITES]], 1);
    }
}

// grid (SCAN_B, 2): y=0 -> cnt_c, y=1 -> cnt_r
__global__ __launch_bounds__(1024) void block_sums(
    const int* __restrict__ cnt_c, const int* __restrict__ cnt_r, int* __restrict__ bsum)
{
    const int* cnt = blockIdx.y ? cnt_r : cnt_c;
    int i = blockIdx.x * 1024 + threadIdx.x;
    int v = (i < N_PAPER) ? cnt[i] : 0;
    __shared__ int sh[16];
    for (int o = 32; o; o >>= 1) v += __shfl_down(v, o);
    if ((threadIdx.x & 63) == 0) sh[threadIdx.x >> 6] = v;
    __syncthreads();
    if (threadIdx.x < 16) {
        int s = sh[threadIdx.x];
        for (int o = 8; o; o >>= 1) s += __shfl_down(s, o);
        if (threadIdx.x == 0) bsum[blockIdx.y * SCAN_B + blockIdx.x] = s;
    }
}

__global__ __launch_bounds__(128) void scan_sums(int* __restrict__ bsum)
{
    __shared__ int sh[2][128];
    int t = threadIdx.x;
    for (int a = 0; a < 2; ++a)
        sh[a][t] = (t < SCAN_B) ? bsum[a * SCAN_B + t] : 0;
    __syncthreads();
    for (int off = 1; off < 128; off <<= 1) {
        int v0 = (t >= off) ? sh[0][t - off] : 0;
        int v1 = (t >= off) ? sh[1][t - off] : 0;
        __syncthreads();
        sh[0][t] += v0; sh[1][t] += v1;
        __syncthreads();
    }
    if (t < SCAN_B) {
        bsum[t]          = (t == 0) ? 0 : sh[0][t - 1];
        bsum[SCAN_B + t] = (t == 0) ? 0 : sh[1][t - 1];
    }
}

// grid (SCAN_B, 2)
__global__ __launch_bounds__(1024) void scan_finalize(
    const int* __restrict__ cnt_c, const int* __restrict__ cnt_r,
    const int* __restrict__ bsum,
    int* __restrict__ rp_c, int* __restrict__ cur_c, float* __restrict__ dinv,
    int* __restrict__ rp_r, int* __restrict__ cur_r)
{
    int a = blockIdx.y;
    const int* cnt = a ? cnt_r : cnt_c;
    int* rp  = a ? rp_r  : rp_c;
    int* cur = a ? cur_r : cur_c;
    __shared__ int sh[1024];
    int t = threadIdx.x;
    int i = blockIdx.x * 1024 + t;
    int v = (i < N_PAPER) ? cnt[i] : 0;
    sh[t] = v;
    __syncthreads();
    for (int off = 1; off < 1024; off <<= 1) {
        int u = (t >= off) ? sh[t - off] : 0;
        __syncthreads();
        sh[t] += u;
        __syncthreads();
    }
    int excl = sh[t] - v + bsum[a * SCAN_B + blockIdx.x];
    if (i < N_PAPER) {
        rp[i] = excl; cur[i] = excl;
        if (!a) dinv[i] = rsqrtf((float)v + 1.0f);
        if (i == N_PAPER - 1) rp[N_PAPER] = excl + v;
    }
}

__global__ __launch_bounds__(256) void scatter_edges(
    const int* __restrict__ cs, const int* __restrict__ cd,
    const int* __restrict__ iss, const int* __restrict__ isd,
    int* __restrict__ cur_c, int* __restrict__ col_c,
    int* __restrict__ cur_r, int* __restrict__ col_r)
{
    int i = blockIdx.x * 256 + threadIdx.x;
    if (i < E_CITES) {
        int pos = atomicAdd(&cur_c[cd[i]], 1);
        col_c[pos] = cs[i];
    } else if (i < E_CITES + E_IS) {
        int e = i - E_CITES;
        int pos = atomicAdd(&cur_r[iss[e]], 1);
        col_r[pos] = isd[e];
    }
}

// ---------------- fp32 -> bf16 convert (vectorized) ----------------
__global__ __launch_bounds__(256) void conv_bf16(
    const float* __restrict__ in, __hip_bfloat16* __restrict__ out, int n4)
{
    int i = blockIdx.x * 256 + threadIdx.x;
    if (i < n4) {
        float4 v = *(const float4*)(in + (size_t)i * 4);
        __hip_bfloat16* o = out + (size_t)i * 4;
        o[0] = __float2bfloat16(v.x); o[1] = __float2bfloat16(v.y);
        o[2] = __float2bfloat16(v.z); o[3] = __float2bfloat16(v.w);
    }
}

// ---------------- W pack into B-fragment order, bf16 ----------------
// Wp[nt][ks][lane][j] = W[ks*32 + (lane>>4)*8 + j][col], col = nt*16 + (lane&15)
// nt in [0, DG/16) -> g (gcn/first matrix), nt in [DG/16, 2*DG/16) -> r (root/second)
__global__ __launch_bounds__(256) void pack_wp(
    const float* __restrict__ g, const float* __restrict__ r,
    __hip_bfloat16* __restrict__ Wp, int DG)
{
    int i = blockIdx.x * 256 + threadIdx.x;
    int total = (2 * DG / 16) * 2048;
    if (i >= total) return;
    int j    = i & 7;
    int lane = (i >> 3) & 63;
    int ks   = (i >> 9) & 3;
    int nt   = i >> 11;
    int k = ks * 32 + (lane >> 4) * 8 + j;
    int c = nt * 16 + (lane & 15);
    float v = (c < DG) ? g[k * DG + c] : r[k * DG + (c - DG)];
    Wp[i] = __float2bfloat16(v);
}

// ---------------- MFMA GEMM: [Hg|Hr] = A[M x 128] @ Wp, bf16 in, bf16 out ----
template<int DG>
__global__ __launch_bounds__(256) void gemm_mfma(
    const __hip_bfloat16* __restrict__ A, const __hip_bfloat16* __restrict__ Wp,
    __hip_bfloat16* __restrict__ Hg, __hip_bfloat16* __restrict__ Hr, int M)
{
    constexpr int NT2 = 2 * DG / 16;
    int tid = threadIdx.x;
    int wv = tid >> 6, lane = tid & 63;
    int m0 = blockIdx.x * 64 + wv * 16;
    int row = m0 + (lane & 15);
    int rowc = min(row, M - 1);
    int kg = lane >> 4;

    bf16x8 a[4];
    const __hip_bfloat16* ap = A + (size_t)rowc * 128 + kg * 8;
    #pragma unroll
    for (int ks = 0; ks < 4; ++ks)
        a[ks] = *(const bf16x8*)(ap + ks * 32);

    f32x4 acc[NT2] = {};
    #pragma unroll
    for (int ks = 0; ks < 4; ++ks) {
        #pragma unroll
        for (int nt = 0; nt < NT2; ++nt) {
            bf16x8 b = *(const bf16x8*)(Wp + ((size_t)(nt * 4 + ks) * 64 + lane) * 8);
            acc[nt] = __builtin_amdgcn_mfma_f32_16x16x32_bf16(a[ks], b, acc[nt], 0, 0, 0);
        }
    }

    int rbase = m0 + (lane >> 4) * 4;
    int c = lane & 15;
    #pragma unroll
    for (int nt = 0; nt < NT2; ++nt) {
        __hip_bfloat16* dst = (nt < DG / 16) ? Hg : Hr;
        int cc = (nt < DG / 16) ? (nt * 16 + c) : ((nt - DG / 16) * 16 + c);
        #pragma unroll
        for (int r = 0; r < 4; ++r) {
            int rr = rbase + r;
            if (rr < M) dst[(size_t)rr * DG + cc] = __float2bfloat16(acc[nt][r]);
        }
    }
}

// ---------------- tiny GEMM (fp32): out[M x N] = X[M x 128] @ W[128 x N] ----
__global__ __launch_bounds__(128) void small_mm(
    const float* __restrict__ X, const float* __restrict__ W,
    float* __restrict__ out, int N)
{
    __shared__ float xrow[128];
    int l = blockIdx.x, t = threadIdx.x;
    xrow[t] = X[(size_t)l * 128 + t];
    __syncthreads();
    if (t < N) {
        float o = 0.f;
        for (int k = 0; k < 128; ++k) o = fmaf(xrow[k], W[k * N + t], o);
        out[(size_t)l * N + t] = o;
    }
}

// ---------------- fused paper-side assembly (bf16 H) ----------------
template<int D, bool RELU, typename OutT>
__global__ __launch_bounds__(256) void paper_assemble(
    const __hip_bfloat16* __restrict__ Hg, const __hip_bfloat16* __restrict__ Hr,
    const int* __restrict__ rp_c, const int* __restrict__ col_c,
    const float* __restrict__ dinv,
    const int* __restrict__ rp_r, const int* __restrict__ col_r,
    const float* __restrict__ yrev,
    const float* __restrict__ gcn_b, const float* __restrict__ rev_relb,
    OutT* __restrict__ out)
{
    constexpr int NB = D / 64;  // bf16 elements per lane
    int w = (int)((blockIdx.x * 256 + threadIdx.x) >> 6);
    if (w >= N_PAPER) return;
    int lane = threadIdx.x & 63;
    int d0 = lane * NB;
    float acc[NB] = {};
    int s = rp_c[w], e = rp_c[w + 1];
    for (int j = s; j < e; ++j) {
        int src = col_c[j];
        float sc = dinv[src];
        if constexpr (NB == 2) {
            unsigned u = *(const unsigned*)(Hg + (size_t)src * D + d0);
            acc[0] = fmaf(sc, bf_lo(u), acc[0]);
            acc[1] = fmaf(sc, bf_hi(u), acc[1]);
        } else {
            acc[0] = fmaf(sc, __bfloat162float(Hg[(size_t)src * D + d0]), acc[0]);
        }
    }
    float di = dinv[w];
    float res[NB];
    #pragma unroll
    for (int b = 0; b < NB; ++b) {
        int d = d0 + b;
        res[b] = di * acc[b]
               + di * di * __bfloat162float(Hg[(size_t)w * D + d])
               + __bfloat162float(Hr[(size_t)w * D + d])
               + gcn_b[d] + rev_relb[d];
    }
    int s2 = rp_r[w], e2 = rp_r[w + 1];
    for (int j = s2; j < e2; ++j) {
        int lab = col_r[j];
        const float* yr = yrev + (size_t)lab * D;
        #pragma unroll
        for (int b = 0; b < NB; ++b) res[b] += yr[d0 + b];
    }
    #pragma unroll
    for (int b = 0; b < NB; ++b) {
        float o = 0.5f * res[b];
        if (RELU) o = fmaxf(o, 0.f);
        if constexpr (sizeof(OutT) == 2)
            out[(size_t)w * D + d0 + b] = __float2bfloat16(o);
        else
            out[(size_t)w * D + d0 + b] = o;
    }
}

// ---------------- label-side: aggregate is-edges onto 128 labels + tiny GEMM --
// Xsrc is bf16 [M x 128]; Xdst fp32 [128 x 128]
template<int DOUT, bool RELU>
__global__ __launch_bounds__(128) void label_kernel(
    const __hip_bfloat16* __restrict__ Xsrc, const float* __restrict__ Xdst,
    const int* __restrict__ iss, const int* __restrict__ isd,
    const float* __restrict__ relW, const float* __restrict__ rootW,
    const float* __restrict__ relb, float* __restrict__ out)
{
    const int CH = 4096;
    __shared__ int list[CH];
    __shared__ int cnt;
    __shared__ float arow[128];
    __shared__ float xrow[128];
    int l = blockIdx.x, t = threadIdx.x;
    float acc = 0.f;
    for (int base = 0; base < E_IS; base += CH) {
        if (t == 0) cnt = 0;
        __syncthreads();
        int nE = min(CH, E_IS - base);
        for (int e = t; e < nE; e += 128) {
            if (isd[base + e] == l) {
                int p = atomicAdd(&cnt, 1);
                list[p] = iss[base + e];
            }
        }
        __syncthreads();
        int c = cnt;
        for (int m = 0; m < c; ++m)
            acc += __bfloat162float(Xsrc[(size_t)list[m] * 128 + t]);
        __syncthreads();
    }
    arow[t] = acc;
    xrow[t] = Xdst[(size_t)l * 128 + t];
    __syncthreads();
    if (t < DOUT) {
        float o = relb[t];
        for (int k = 0; k < 128; ++k)
            o = fmaf(arow[k], relW[k * DOUT + t], fmaf(xrow[k], rootW[k * DOUT + t], o));
        if (RELU) o = fmaxf(o, 0.f);
        out[(size_t)l * DOUT + t] = o;
    }
}

extern "C" void kernel_launch(void* const* d_in, const int* in_sizes, int n_in,
                              void* d_out, int out_size, void* d_ws, size_t ws_size,
                              hipStream_t stream)
{
    const float* xp          = (const float*)d_in[0];
    const float* xl          = (const float*)d_in[1];
    const int*   cs          = (const int*)d_in[2];
    const int*   cd          = (const int*)d_in[3];
    const int*   iss         = (const int*)d_in[4];
    const int*   isd         = (const int*)d_in[5];
    const float* l1_gcn_W    = (const float*)d_in[6];
    const float* l1_gcn_b    = (const float*)d_in[7];
    const float* l1_is_relW  = (const float*)d_in[8];
    const float* l1_is_relb  = (const float*)d_in[9];
    const float* l1_is_rootW = (const float*)d_in[10];
    const float* l1_rev_relW = (const float*)d_in[11];
    const float* l1_rev_relb = (const float*)d_in[12];
    const float* l1_rev_rootW= (const float*)d_in[13];
    const float* l2_gcn_W    = (const float*)d_in[14];
    const float* l2_gcn_b    = (const float*)d_in[15];
    const float* l2_is_relW  = (const float*)d_in[16];
    const float* l2_is_relb  = (const float*)d_in[17];
    const float* l2_is_rootW = (const float*)d_in[18];
    const float* l2_rev_relW = (const float*)d_in[19];
    const float* l2_rev_relb = (const float*)d_in[20];
    const float* l2_rev_rootW= (const float*)d_in[21];

    char* ws = (char*)d_ws;
    size_t off = 0;
    auto alloc = [&](size_t bytes) {
        char* p = ws + off;
        off += (bytes + 255) & ~(size_t)255;
        return p;
    };
    __hip_bfloat16* xp_bf = (__hip_bfloat16*)alloc((size_t)N_PAPER * 128 * 2);
    __hip_bfloat16* hp1   = (__hip_bfloat16*)alloc((size_t)N_PAPER * 128 * 2);
    __hip_bfloat16* Hg    = (__hip_bfloat16*)alloc((size_t)N_PAPER * 128 * 2);
    __hip_bfloat16* Hr    = (__hip_bfloat16*)alloc((size_t)N_PAPER * 128 * 2);
    int*   col_c = (int*)alloc((size_t)E_CITES * 4);
    int*   col_r = (int*)alloc((size_t)E_IS * 4);
    int*   rp_c  = (int*)alloc((size_t)(N_PAPER + 1) * 4);
    int*   cur_c = (int*)alloc((size_t)(N_PAPER + 1) * 4);
    int*   rp_r  = (int*)alloc((size_t)(N_PAPER + 1) * 4);
    int*   cur_r = (int*)alloc((size_t)(N_PAPER + 1) * 4);
    int*   cnt_c = (int*)alloc((size_t)N_PAPER * 4);
    int*   cnt_r = (int*)alloc((size_t)N_PAPER * 4);
    float* dinv  = (float*)alloc((size_t)N_PAPER * 4);
    int*   bsum  = (int*)alloc((size_t)2 * SCAN_B * 4);
    __hip_bfloat16* Wp1 = (__hip_bfloat16*)alloc((size_t)32768 * 2);
    __hip_bfloat16* Wp2 = (__hip_bfloat16*)alloc((size_t)16384 * 2);
    float* yrev1 = (float*)alloc(128 * 128 * 4);
    float* yrev2 = (float*)alloc(128 * 64 * 4);
    float* hl1   = (float*)alloc(128 * 128 * 4);

    float* zp = (float*)d_out;                          // [100000 x 64]
    float* zl = (float*)d_out + (size_t)N_PAPER * 64;   // [128 x 64]

    hipMemsetAsync(cnt_c, 0, (size_t)N_PAPER * 4, stream);
    hipMemsetAsync(cnt_r, 0, (size_t)N_PAPER * 4, stream);

    int eTot = E_CITES + E_IS;
    count_edges<<<(eTot + 255) / 256, 256, 0, stream>>>(cd, iss, cnt_c, cnt_r);
    block_sums<<<dim3(SCAN_B, 2), 1024, 0, stream>>>(cnt_c, cnt_r, bsum);
    scan_sums<<<1, 128, 0, stream>>>(bsum);
    scan_finalize<<<dim3(SCAN_B, 2), 1024, 0, stream>>>(
        cnt_c, cnt_r, bsum, rp_c, cur_c, dinv, rp_r, cur_r);
    scatter_edges<<<(eTot + 255) / 256, 256, 0, stream>>>(cs, cd, iss, isd,
                                                          cur_c, col_c, cur_r, col_r);
    conv_bf16<<<(N_PAPER * 128 / 4 + 255) / 256, 256, 0, stream>>>(xp, xp_bf, N_PAPER * 128 / 4);
    pack_wp<<<(32768 + 255) / 256, 256, 0, stream>>>(l1_gcn_W, l1_rev_rootW, Wp1, 128);
    pack_wp<<<(16384 + 255) / 256, 256, 0, stream>>>(l2_gcn_W, l2_rev_rootW, Wp2, 64);
    small_mm<<<128, 128, 0, stream>>>(xl, l1_rev_relW, yrev1, 128);

    // ---- layer 1 ----
    gemm_mfma<128><<<(N_PAPER + 63) / 64, 256, 0, stream>>>(xp_bf, Wp1, Hg, Hr, N_PAPER);
    paper_assemble<128, true, __hip_bfloat16><<<(N_PAPER + 3) / 4, 256, 0, stream>>>(
        Hg, Hr, rp_c, col_c, dinv, rp_r, col_r, yrev1, l1_gcn_b, l1_rev_relb, hp1);
    label_kernel<128, true><<<N_LABEL, 128, 0, stream>>>(
        xp_bf, xl, iss, isd, l1_is_relW, l1_is_rootW, l1_is_relb, hl1);
    small_mm<<<128, 128, 0, stream>>>(hl1, l2_rev_relW, yrev2, 64);

    // ---- layer 2 ----
    gemm_mfma<64><<<(N_PAPER + 63) / 64, 256, 0, stream>>>(hp1, Wp2, Hg, Hr, N_PAPER);
    paper_assemble<64, false, float><<<(N_PAPER + 3) / 4, 256, 0, stream>>>(
        Hg, Hr, rp_c, col_c, dinv, rp_r, col_r, yrev2, l2_gcn_b, l2_rev_relb, zp);
    label_kernel<64, false><<<N_LABEL, 128, 0, stream>>>(
        hp1, hl1, iss, isd, l2_is_relW, l2_is_rootW, l2_is_relb, zl);
}

// Round 3
// 852.728 us; speedup vs baseline: 2.0467x; 1.3557x over previous
//
#include <hip/hip_runtime.h>
#include <hip/hip_bf16.h>

#define N_PAPER 100000
#define N_LABEL 128
#define E_CITES 1600000
#define E_IS    100000
#define SCAN_B  98   // ceil(100000/1024)
#define LSPLIT  8

typedef __bf16 bf16x8 __attribute__((ext_vector_type(8)));
typedef float  f32x4  __attribute__((ext_vector_type(4)));

static __device__ __forceinline__ float bf_lo(unsigned u) {
    union { unsigned u; float f; } v; v.u = u << 16; return v.f;
}
static __device__ __forceinline__ float bf_hi(unsigned u) {
    union { unsigned u; float f; } v; v.u = u & 0xffff0000u; return v.f;
}

// ---------------- CSR build ----------------
__global__ __launch_bounds__(256) void count_edges(
    const int* __restrict__ cd, const int* __restrict__ iss, const int* __restrict__ isd,
    int* __restrict__ cnt_c, int* __restrict__ cnt_r, int* __restrict__ cnt_l)
{
    int i = blockIdx.x * 256 + threadIdx.x;
    if (i < E_CITES) {
        atomicAdd(&cnt_c[cd[i]], 1);
    } else if (i < E_CITES + E_IS) {
        int e = i - E_CITES;
        atomicAdd(&cnt_r[iss[e]], 1);
        atomicAdd(&cnt_l[isd[e]], 1);
    }
}

// grid (SCAN_B, 2): y=0 -> cnt_c, y=1 -> cnt_r
__global__ __launch_bounds__(1024) void block_sums(
    const int* __restrict__ cnt_c, const int* __restrict__ cnt_r, int* __restrict__ bsum)
{
    const int* cnt = blockIdx.y ? cnt_r : cnt_c;
    int i = blockIdx.x * 1024 + threadIdx.x;
    int v = (i < N_PAPER) ? cnt[i] : 0;
    __shared__ int sh[16];
    for (int o = 32; o; o >>= 1) v += __shfl_down(v, o);
    if ((threadIdx.x & 63) == 0) sh[threadIdx.x >> 6] = v;
    __syncthreads();
    if (threadIdx.x < 16) {
        int s = sh[threadIdx.x];
        for (int o = 8; o; o >>= 1) s += __shfl_down(s, o);
        if (threadIdx.x == 0) bsum[blockIdx.y * SCAN_B + blockIdx.x] = s;
    }
}

// single block: scan the two 98-entry block-sum arrays + the 128-entry label counts
__global__ __launch_bounds__(128) void scan_sums(
    int* __restrict__ bsum, const int* __restrict__ cnt_l,
    int* __restrict__ rp_l, int* __restrict__ cur_l)
{
    __shared__ int sh[3][128];
    int t = threadIdx.x;
    sh[0][t] = (t < SCAN_B) ? bsum[t] : 0;
    sh[1][t] = (t < SCAN_B) ? bsum[SCAN_B + t] : 0;
    sh[2][t] = cnt_l[t];
    __syncthreads();
    for (int off = 1; off < 128; off <<= 1) {
        int v0 = (t >= off) ? sh[0][t - off] : 0;
        int v1 = (t >= off) ? sh[1][t - off] : 0;
        int v2 = (t >= off) ? sh[2][t - off] : 0;
        __syncthreads();
        sh[0][t] += v0; sh[1][t] += v1; sh[2][t] += v2;
        __syncthreads();
    }
    if (t < SCAN_B) {
        bsum[t]          = (t == 0) ? 0 : sh[0][t - 1];
        bsum[SCAN_B + t] = (t == 0) ? 0 : sh[1][t - 1];
    }
    int e = (t == 0) ? 0 : sh[2][t - 1];
    rp_l[t] = e; cur_l[t] = e;
    if (t == 127) rp_l[128] = sh[2][127];
}

// grid (SCAN_B, 2)
__global__ __launch_bounds__(1024) void scan_finalize(
    const int* __restrict__ cnt_c, const int* __restrict__ cnt_r,
    const int* __restrict__ bsum,
    int* __restrict__ rp_c, int* __restrict__ cur_c, float* __restrict__ dinv,
    int* __restrict__ rp_r, int* __restrict__ cur_r)
{
    int a = blockIdx.y;
    const int* cnt = a ? cnt_r : cnt_c;
    int* rp  = a ? rp_r  : rp_c;
    int* cur = a ? cur_r : cur_c;
    __shared__ int sh[1024];
    int t = threadIdx.x;
    int i = blockIdx.x * 1024 + t;
    int v = (i < N_PAPER) ? cnt[i] : 0;
    sh[t] = v;
    __syncthreads();
    for (int off = 1; off < 1024; off <<= 1) {
        int u = (t >= off) ? sh[t - off] : 0;
        __syncthreads();
        sh[t] += u;
        __syncthreads();
    }
    int excl = sh[t] - v + bsum[a * SCAN_B + blockIdx.x];
    if (i < N_PAPER) {
        rp[i] = excl; cur[i] = excl;
        if (!a) dinv[i] = rsqrtf((float)v + 1.0f);
        if (i == N_PAPER - 1) rp[N_PAPER] = excl + v;
    }
}

__global__ __launch_bounds__(256) void scatter_edges(
    const int* __restrict__ cs, const int* __restrict__ cd,
    const int* __restrict__ iss, const int* __restrict__ isd,
    int* __restrict__ cur_c, int* __restrict__ col_c,
    int* __restrict__ cur_r, int* __restrict__ col_r,
    int* __restrict__ cur_l, int* __restrict__ col_l)
{
    int i = blockIdx.x * 256 + threadIdx.x;
    if (i < E_CITES) {
        int pos = atomicAdd(&cur_c[cd[i]], 1);
        col_c[pos] = cs[i];
    } else if (i < E_CITES + E_IS) {
        int e = i - E_CITES;
        int pos = atomicAdd(&cur_r[iss[e]], 1);
        col_r[pos] = isd[e];
        int pos2 = atomicAdd(&cur_l[isd[e]], 1);
        col_l[pos2] = iss[e];
    }
}

// ---------------- fp32 -> bf16 convert (vectorized) ----------------
__global__ __launch_bounds__(256) void conv_bf16(
    const float* __restrict__ in, __hip_bfloat16* __restrict__ out, int n4)
{
    int i = blockIdx.x * 256 + threadIdx.x;
    if (i < n4) {
        float4 v = *(const float4*)(in + (size_t)i * 4);
        __hip_bfloat16* o = out + (size_t)i * 4;
        o[0] = __float2bfloat16(v.x); o[1] = __float2bfloat16(v.y);
        o[2] = __float2bfloat16(v.z); o[3] = __float2bfloat16(v.w);
    }
}

// ---------------- W pack into B-fragment order, bf16 ----------------
// Wp[nt][ks][lane][j] = W[ks*32 + (lane>>4)*8 + j][col], col = nt*16 + (lane&15)
__global__ __launch_bounds__(256) void pack_wp(
    const float* __restrict__ g, const float* __restrict__ r,
    __hip_bfloat16* __restrict__ Wp, int DG)
{
    int i = blockIdx.x * 256 + threadIdx.x;
    int total = (2 * DG / 16) * 2048;
    if (i >= total) return;
    int j    = i & 7;
    int lane = (i >> 3) & 63;
    int ks   = (i >> 9) & 3;
    int nt   = i >> 11;
    int k = ks * 32 + (lane >> 4) * 8 + j;
    int c = nt * 16 + (lane & 15);
    float v = (c < DG) ? g[k * DG + c] : r[k * DG + (c - DG)];
    Wp[i] = __float2bfloat16(v);
}

// ---------------- MFMA GEMM: [Hg|Hr] = A[M x 128] @ Wp, bf16 in, bf16 out ----
template<int DG>
__global__ __launch_bounds__(256) void gemm_mfma(
    const __hip_bfloat16* __restrict__ A, const __hip_bfloat16* __restrict__ Wp,
    __hip_bfloat16* __restrict__ Hg, __hip_bfloat16* __restrict__ Hr, int M)
{
    constexpr int NT2 = 2 * DG / 16;
    int tid = threadIdx.x;
    int wv = tid >> 6, lane = tid & 63;
    int m0 = blockIdx.x * 64 + wv * 16;
    int row = m0 + (lane & 15);
    int rowc = min(row, M - 1);
    int kg = lane >> 4;

    bf16x8 a[4];
    const __hip_bfloat16* ap = A + (size_t)rowc * 128 + kg * 8;
    #pragma unroll
    for (int ks = 0; ks < 4; ++ks)
        a[ks] = *(const bf16x8*)(ap + ks * 32);

    f32x4 acc[NT2] = {};
    #pragma unroll
    for (int ks = 0; ks < 4; ++ks) {
        #pragma unroll
        for (int nt = 0; nt < NT2; ++nt) {
            bf16x8 b = *(const bf16x8*)(Wp + ((size_t)(nt * 4 + ks) * 64 + lane) * 8);
            acc[nt] = __builtin_amdgcn_mfma_f32_16x16x32_bf16(a[ks], b, acc[nt], 0, 0, 0);
        }
    }

    int rbase = m0 + (lane >> 4) * 4;
    int c = lane & 15;
    #pragma unroll
    for (int nt = 0; nt < NT2; ++nt) {
        __hip_bfloat16* dst = (nt < DG / 16) ? Hg : Hr;
        int cc = (nt < DG / 16) ? (nt * 16 + c) : ((nt - DG / 16) * 16 + c);
        #pragma unroll
        for (int r = 0; r < 4; ++r) {
            int rr = rbase + r;
            if (rr < M) dst[(size_t)rr * DG + cc] = __float2bfloat16(acc[nt][r]);
        }
    }
}

// ---------------- tiny GEMM (fp32): out[M x N] = X[M x 128] @ W[128 x N] ----
__global__ __launch_bounds__(128) void small_mm(
    const float* __restrict__ X, const float* __restrict__ W,
    float* __restrict__ out, int N)
{
    __shared__ float xrow[128];
    int l = blockIdx.x, t = threadIdx.x;
    xrow[t] = X[(size_t)l * 128 + t];
    __syncthreads();
    if (t < N) {
        float o = 0.f;
        for (int k = 0; k < 128; ++k) o = fmaf(xrow[k], W[k * N + t], o);
        out[(size_t)l * N + t] = o;
    }
}

// ---------------- fused paper-side assembly (bf16 H) ----------------
template<int D, bool RELU, typename OutT>
__global__ __launch_bounds__(256) void paper_assemble(
    const __hip_bfloat16* __restrict__ Hg, const __hip_bfloat16* __restrict__ Hr,
    const int* __restrict__ rp_c, const int* __restrict__ col_c,
    const float* __restrict__ dinv,
    const int* __restrict__ rp_r, const int* __restrict__ col_r,
    const float* __restrict__ yrev,
    const float* __restrict__ gcn_b, const float* __restrict__ rev_relb,
    OutT* __restrict__ out)
{
    constexpr int NB = D / 64;  // bf16 elements per lane
    int w = (int)((blockIdx.x * 256 + threadIdx.x) >> 6);
    if (w >= N_PAPER) return;
    int lane = threadIdx.x & 63;
    int d0 = lane * NB;
    float acc[NB] = {};
    int s = rp_c[w], e = rp_c[w + 1];
    for (int j = s; j < e; ++j) {
        int src = col_c[j];
        float sc = dinv[src];
        if constexpr (NB == 2) {
            unsigned u = *(const unsigned*)(Hg + (size_t)src * D + d0);
            acc[0] = fmaf(sc, bf_lo(u), acc[0]);
            acc[1] = fmaf(sc, bf_hi(u), acc[1]);
        } else {
            acc[0] = fmaf(sc, __bfloat162float(Hg[(size_t)src * D + d0]), acc[0]);
        }
    }
    float di = dinv[w];
    float res[NB];
    #pragma unroll
    for (int b = 0; b < NB; ++b) {
        int d = d0 + b;
        res[b] = di * acc[b]
               + di * di * __bfloat162float(Hg[(size_t)w * D + d])
               + __bfloat162float(Hr[(size_t)w * D + d])
               + gcn_b[d] + rev_relb[d];
    }
    int s2 = rp_r[w], e2 = rp_r[w + 1];
    for (int j = s2; j < e2; ++j) {
        int lab = col_r[j];
        const float* yr = yrev + (size_t)lab * D;
        #pragma unroll
        for (int b = 0; b < NB; ++b) res[b] += yr[d0 + b];
    }
    #pragma unroll
    for (int b = 0; b < NB; ++b) {
        float o = 0.5f * res[b];
        if (RELU) o = fmaxf(o, 0.f);
        if constexpr (sizeof(OutT) == 2)
            out[(size_t)w * D + d0 + b] = __float2bfloat16(o);
        else
            out[(size_t)w * D + d0 + b] = o;
    }
}

// ---------------- label-side aggregation via CSR (grid: 128 labels x LSPLIT) --
__global__ __launch_bounds__(128) void label_agg(
    const __hip_bfloat16* __restrict__ Xsrc,
    const int* __restrict__ rp_l, const int* __restrict__ col_l,
    float* __restrict__ partialL)
{
    int l = blockIdx.x, sp = blockIdx.y, t = threadIdx.x;
    int s = rp_l[l], e = rp_l[l + 1];
    int n = e - s;
    int per = (n + LSPLIT - 1) / LSPLIT;
    int b = s + sp * per;
    int en = min(b + per, e);
    float acc = 0.f;
    for (int m = b; m < en; ++m)
        acc += __bfloat162float(Xsrc[(size_t)col_l[m] * 128 + t]);
    partialL[((size_t)l * LSPLIT + sp) * 128 + t] = acc;
}

// ---------------- label-side finish: sum partials + tiny GEMM ----------------
// out[l] = [relu]( aggL[l] @ relW + Xdst[l] @ rootW + relb )
template<int DOUT, bool RELU>
__global__ __launch_bounds__(128) void label_finish(
    const float* __restrict__ partialL, const float* __restrict__ Xdst,
    const float* __restrict__ relW, const float* __restrict__ rootW,
    const float* __restrict__ relb, float* __restrict__ out)
{
    __shared__ float arow[128];
    __shared__ float xrow[128];
    int l = blockIdx.x, t = threadIdx.x;
    float a = 0.f;
    #pragma unroll
    for (int sp = 0; sp < LSPLIT; ++sp)
        a += partialL[((size_t)l * LSPLIT + sp) * 128 + t];
    arow[t] = a;
    xrow[t] = Xdst[(size_t)l * 128 + t];
    __syncthreads();
    if (t < DOUT) {
        float o = relb[t];
        for (int k = 0; k < 128; ++k)
            o = fmaf(arow[k], relW[k * DOUT + t], fmaf(xrow[k], rootW[k * DOUT + t], o));
        if (RELU) o = fmaxf(o, 0.f);
        out[(size_t)l * DOUT + t] = o;
    }
}

extern "C" void kernel_launch(void* const* d_in, const int* in_sizes, int n_in,
                              void* d_out, int out_size, void* d_ws, size_t ws_size,
                              hipStream_t stream)
{
    const float* xp          = (const float*)d_in[0];
    const float* xl          = (const float*)d_in[1];
    const int*   cs          = (const int*)d_in[2];
    const int*   cd          = (const int*)d_in[3];
    const int*   iss         = (const int*)d_in[4];
    const int*   isd         = (const int*)d_in[5];
    const float* l1_gcn_W    = (const float*)d_in[6];
    const float* l1_gcn_b    = (const float*)d_in[7];
    const float* l1_is_relW  = (const float*)d_in[8];
    const float* l1_is_relb  = (const float*)d_in[9];
    const float* l1_is_rootW = (const float*)d_in[10];
    const float* l1_rev_relW = (const float*)d_in[11];
    const float* l1_rev_relb = (const float*)d_in[12];
    const float* l1_rev_rootW= (const float*)d_in[13];
    const float* l2_gcn_W    = (const float*)d_in[14];
    const float* l2_gcn_b    = (const float*)d_in[15];
    const float* l2_is_relW  = (const float*)d_in[16];
    const float* l2_is_relb  = (const float*)d_in[17];
    const float* l2_is_rootW = (const float*)d_in[18];
    const float* l2_rev_relW = (const float*)d_in[19];
    const float* l2_rev_relb = (const float*)d_in[20];
    const float* l2_rev_rootW= (const float*)d_in[21];

    char* ws = (char*)d_ws;
    size_t off = 0;
    auto alloc = [&](size_t bytes) {
        char* p = ws + off;
        off += (bytes + 255) & ~(size_t)255;
        return p;
    };
    __hip_bfloat16* xp_bf = (__hip_bfloat16*)alloc((size_t)N_PAPER * 128 * 2);
    __hip_bfloat16* hp1   = (__hip_bfloat16*)alloc((size_t)N_PAPER * 128 * 2);
    __hip_bfloat16* Hg    = (__hip_bfloat16*)alloc((size_t)N_PAPER * 128 * 2);
    __hip_bfloat16* Hr    = (__hip_bfloat16*)alloc((size_t)N_PAPER * 128 * 2);
    int*   col_c = (int*)alloc((size_t)E_CITES * 4);
    int*   col_r = (int*)alloc((size_t)E_IS * 4);
    int*   col_l = (int*)alloc((size_t)E_IS * 4);
    int*   rp_c  = (int*)alloc((size_t)(N_PAPER + 1) * 4);
    int*   cur_c = (int*)alloc((size_t)(N_PAPER + 1) * 4);
    int*   rp_r  = (int*)alloc((size_t)(N_PAPER + 1) * 4);
    int*   cur_r = (int*)alloc((size_t)(N_PAPER + 1) * 4);
    int*   rp_l  = (int*)alloc((size_t)(N_LABEL + 1) * 4);
    int*   cur_l = (int*)alloc((size_t)N_LABEL * 4);
    int*   cnt_c = (int*)alloc((size_t)N_PAPER * 4);
    int*   cnt_r = (int*)alloc((size_t)N_PAPER * 4);
    int*   cnt_l = (int*)alloc((size_t)N_LABEL * 4);
    float* dinv  = (float*)alloc((size_t)N_PAPER * 4);
    int*   bsum  = (int*)alloc((size_t)2 * SCAN_B * 4);
    __hip_bfloat16* Wp1 = (__hip_bfloat16*)alloc((size_t)32768 * 2);
    __hip_bfloat16* Wp2 = (__hip_bfloat16*)alloc((size_t)16384 * 2);
    float* yrev1 = (float*)alloc(128 * 128 * 4);
    float* yrev2 = (float*)alloc(128 * 64 * 4);
    float* hl1   = (float*)alloc(128 * 128 * 4);
    float* partialL = (float*)alloc((size_t)N_LABEL * LSPLIT * 128 * 4);

    float* zp = (float*)d_out;                          // [100000 x 64]
    float* zl = (float*)d_out + (size_t)N_PAPER * 64;   // [128 x 64]

    hipMemsetAsync(cnt_c, 0, (size_t)N_PAPER * 4, stream);
    hipMemsetAsync(cnt_r, 0, (size_t)N_PAPER * 4, stream);
    hipMemsetAsync(cnt_l, 0, (size_t)N_LABEL * 4, stream);

    int eTot = E_CITES + E_IS;
    count_edges<<<(eTot + 255) / 256, 256, 0, stream>>>(cd, iss, isd, cnt_c, cnt_r, cnt_l);
    block_sums<<<dim3(SCAN_B, 2), 1024, 0, stream>>>(cnt_c, cnt_r, bsum);
    scan_sums<<<1, 128, 0, stream>>>(bsum, cnt_l, rp_l, cur_l);
    scan_finalize<<<dim3(SCAN_B, 2), 1024, 0, stream>>>(
        cnt_c, cnt_r, bsum, rp_c, cur_c, dinv, rp_r, cur_r);
    scatter_edges<<<(eTot + 255) / 256, 256, 0, stream>>>(
        cs, cd, iss, isd, cur_c, col_c, cur_r, col_r, cur_l, col_l);
    conv_bf16<<<(N_PAPER * 128 / 4 + 255) / 256, 256, 0, stream>>>(xp, xp_bf, N_PAPER * 128 / 4);
    pack_wp<<<(32768 + 255) / 256, 256, 0, stream>>>(l1_gcn_W, l1_rev_rootW, Wp1, 128);
    pack_wp<<<(16384 + 255) / 256, 256, 0, stream>>>(l2_gcn_W, l2_rev_rootW, Wp2, 64);
    small_mm<<<128, 128, 0, stream>>>(xl, l1_rev_relW, yrev1, 128);

    // ---- layer 1 ----
    gemm_mfma<128><<<(N_PAPER + 63) / 64, 256, 0, stream>>>(xp_bf, Wp1, Hg, Hr, N_PAPER);
    paper_assemble<128, true, __hip_bfloat16><<<(N_PAPER + 3) / 4, 256, 0, stream>>>(
        Hg, Hr, rp_c, col_c, dinv, rp_r, col_r, yrev1, l1_gcn_b, l1_rev_relb, hp1);
    label_agg<<<dim3(N_LABEL, LSPLIT), 128, 0, stream>>>(xp_bf, rp_l, col_l, partialL);
    label_finish<128, true><<<N_LABEL, 128, 0, stream>>>(
        partialL, xl, l1_is_relW, l1_is_rootW, l1_is_relb, hl1);
    small_mm<<<128, 128, 0, stream>>>(hl1, l2_rev_relW, yrev2, 64);

    // ---- layer 2 ----
    gemm_mfma<64><<<(N_PAPER + 63) / 64, 256, 0, stream>>>(hp1, Wp2, Hg, Hr, N_PAPER);
    paper_assemble<64, false, float><<<(N_PAPER + 3) / 4, 256, 0, stream>>>(
        Hg, Hr, rp_c, col_c, dinv, rp_r, col_r, yrev2, l2_gcn_b, l2_rev_relb, zp);
    label_agg<<<dim3(N_LABEL, LSPLIT), 128, 0, stream>>>(hp1, rp_l, col_l, partialL);
    label_finish<64, false><<<N_LABEL, 128, 0, stream>>>(
        partialL, hl1, l2_is_relW, l2_is_rootW, l2_is_relb, zl);
}

// Round 4
// 722.821 us; speedup vs baseline: 2.4146x; 1.1797x over previous
//
#include <hip/hip_runtime.h>
#include <hip/hip_bf16.h>

#define N_PAPER 100000
#define N_LABEL 128
#define E_CITES 1600000
#define E_IS    100000
#define SCAN_B  98   // ceil(100000/1024)
#define NBKT    98   // dst>>10 buckets
#define A2_CHUNK 2048
#define LSPLIT  8

typedef __bf16 bf16x8 __attribute__((ext_vector_type(8)));
typedef float  f32x4  __attribute__((ext_vector_type(4)));

static __device__ __forceinline__ float bf_lo(unsigned u) {
    union { unsigned u; float f; } v; v.u = u << 16; return v.f;
}
static __device__ __forceinline__ float bf_hi(unsigned u) {
    union { unsigned u; float f; } v; v.u = u & 0xffff0000u; return v.f;
}

// ---------------- cites: coarse bucket histogram ----------------
__global__ __launch_bounds__(256) void bucket_count(
    const int* __restrict__ cd, int* __restrict__ bhist)
{
    __shared__ int h[NBKT];
    int t = threadIdx.x;
    if (t < NBKT) h[t] = 0;
    __syncthreads();
    for (int i = blockIdx.x * 256 + t; i < E_CITES; i += gridDim.x * 256)
        atomicAdd(&h[cd[i] >> 10], 1);
    __syncthreads();
    if (t < NBKT && h[t]) atomicAdd(&bhist[t], h[t]);
}

// ---------------- is-edges: per-node counts ----------------
__global__ __launch_bounds__(256) void count_is(
    const int* __restrict__ iss, const int* __restrict__ isd,
    int* __restrict__ cnt_r, int* __restrict__ cnt_l)
{
    int i = blockIdx.x * 256 + threadIdx.x;
    if (i < E_IS) {
        atomicAdd(&cnt_r[iss[i]], 1);
        atomicAdd(&cnt_l[isd[i]], 1);
    }
}

// grid SCAN_B: block sums of cnt_r
__global__ __launch_bounds__(1024) void block_sums(
    const int* __restrict__ cnt_r, int* __restrict__ bsum)
{
    int i = blockIdx.x * 1024 + threadIdx.x;
    int v = (i < N_PAPER) ? cnt_r[i] : 0;
    __shared__ int sh[16];
    for (int o = 32; o; o >>= 1) v += __shfl_down(v, o);
    if ((threadIdx.x & 63) == 0) sh[threadIdx.x >> 6] = v;
    __syncthreads();
    if (threadIdx.x < 16) {
        int s = sh[threadIdx.x];
        for (int o = 8; o; o >>= 1) s += __shfl_down(s, o);
        if (threadIdx.x == 0) bsum[blockIdx.x] = s;
    }
}

// single block: scan bsum(98) + cnt_l(128) + bhist(98)
__global__ __launch_bounds__(128) void scan_sums(
    int* __restrict__ bsum, const int* __restrict__ cnt_l,
    int* __restrict__ rp_l, int* __restrict__ cur_l,
    const int* __restrict__ bhist, int* __restrict__ bbase, int* __restrict__ bcur)
{
    __shared__ int sh[3][128];
    int t = threadIdx.x;
    sh[0][t] = (t < SCAN_B) ? bsum[t] : 0;
    sh[1][t] = cnt_l[t];
    sh[2][t] = (t < NBKT) ? bhist[t] : 0;
    __syncthreads();
    for (int off = 1; off < 128; off <<= 1) {
        int v0 = (t >= off) ? sh[0][t - off] : 0;
        int v1 = (t >= off) ? sh[1][t - off] : 0;
        int v2 = (t >= off) ? sh[2][t - off] : 0;
        __syncthreads();
        sh[0][t] += v0; sh[1][t] += v1; sh[2][t] += v2;
        __syncthreads();
    }
    if (t < SCAN_B) bsum[t] = (t == 0) ? 0 : sh[0][t - 1];
    int e = (t == 0) ? 0 : sh[1][t - 1];
    rp_l[t] = e; cur_l[t] = e;
    if (t == 127) rp_l[128] = sh[1][127];
    if (t < NBKT) {
        int b = (t == 0) ? 0 : sh[2][t - 1];
        bbase[t] = b; bcur[t] = b;
        if (t == NBKT - 1) bbase[NBKT] = sh[2][t];
    }
}

// grid SCAN_B: full scan of cnt_r -> rp_r/cur_r
__global__ __launch_bounds__(1024) void scan_finalize(
    const int* __restrict__ cnt_r, const int* __restrict__ bsum,
    int* __restrict__ rp_r, int* __restrict__ cur_r)
{
    __shared__ int sh[1024];
    int t = threadIdx.x;
    int i = blockIdx.x * 1024 + t;
    int v = (i < N_PAPER) ? cnt_r[i] : 0;
    sh[t] = v;
    __syncthreads();
    for (int off = 1; off < 1024; off <<= 1) {
        int u = (t >= off) ? sh[t - off] : 0;
        __syncthreads();
        sh[t] += u;
        __syncthreads();
    }
    int excl = sh[t] - v + bsum[blockIdx.x];
    if (i < N_PAPER) {
        rp_r[i] = excl; cur_r[i] = excl;
        if (i == N_PAPER - 1) rp_r[N_PAPER] = excl + v;
    }
}

// ---------------- cites: bucketed edge scatter (packed u32) ----------------
__global__ __launch_bounds__(256) void bucket_scatter(
    const int* __restrict__ cs, const int* __restrict__ cd,
    int* __restrict__ bcur, unsigned* __restrict__ ebuf)
{
    __shared__ int sd[A2_CHUNK];
    __shared__ int ss[A2_CHUNK];
    __shared__ int h[NBKT], base[NBKT], cur[NBKT];
    int t = threadIdx.x;
    int e0 = blockIdx.x * A2_CHUNK;
    int n = min(A2_CHUNK, E_CITES - e0);
    if (t < NBKT) h[t] = 0;
    __syncthreads();
    for (int i = t; i < n; i += 256) {
        int d = cd[e0 + i], s = cs[e0 + i];
        sd[i] = d; ss[i] = s;
        atomicAdd(&h[d >> 10], 1);
    }
    __syncthreads();
    if (t < NBKT) { base[t] = atomicAdd(&bcur[t], h[t]); cur[t] = 0; }
    __syncthreads();
    for (int i = t; i < n; i += 256) {
        int b = sd[i] >> 10;
        int p = base[b] + atomicAdd(&cur[b], 1);
        ebuf[p] = ((unsigned)(sd[i] & 1023) << 17) | (unsigned)ss[i];
    }
}

// ---------------- cites: per-bucket CSR build (one block per bucket) --------
__global__ __launch_bounds__(1024) void bucket_csr(
    const unsigned* __restrict__ ebuf, const int* __restrict__ bbase,
    int* __restrict__ rp_c, int* __restrict__ col_c, float* __restrict__ dinv)
{
    __shared__ int hist[1024];
    __shared__ int sc[1024];
    int b = blockIdx.x, t = threadIdx.x;
    int s = bbase[b], e = bbase[b + 1];
    hist[t] = 0;
    __syncthreads();
    for (int i = s + t; i < e; i += 1024)
        atomicAdd(&hist[ebuf[i] >> 17], 1);
    __syncthreads();
    int v = hist[t];
    sc[t] = v;
    __syncthreads();
    for (int off = 1; off < 1024; off <<= 1) {
        int u = (t >= off) ? sc[t - off] : 0;
        __syncthreads();
        sc[t] += u;
        __syncthreads();
    }
    int excl = sc[t] - v;
    int node = b * 1024 + t;
    if (node < N_PAPER) {
        rp_c[node] = s + excl;
        dinv[node] = rsqrtf((float)v + 1.0f);
        if (node == N_PAPER - 1) rp_c[N_PAPER] = s + excl + v;
    }
    __syncthreads();
    hist[t] = s + excl;   // reuse as running cursor
    __syncthreads();
    for (int i = s + t; i < e; i += 1024) {
        unsigned u = ebuf[i];
        int p = atomicAdd(&hist[u >> 17], 1);
        col_c[p] = (int)(u & 0x1FFFFu);
    }
}

// ---------------- is-edges scatter (small) ----------------
__global__ __launch_bounds__(256) void scatter_is(
    const int* __restrict__ iss, const int* __restrict__ isd,
    int* __restrict__ cur_r, int* __restrict__ col_r,
    int* __restrict__ cur_l, int* __restrict__ col_l)
{
    int i = blockIdx.x * 256 + threadIdx.x;
    if (i < E_IS) {
        int pos = atomicAdd(&cur_r[iss[i]], 1);
        col_r[pos] = isd[i];
        int pos2 = atomicAdd(&cur_l[isd[i]], 1);
        col_l[pos2] = iss[i];
    }
}

// ---------------- fp32 -> bf16 convert (vectorized) ----------------
__global__ __launch_bounds__(256) void conv_bf16(
    const float* __restrict__ in, __hip_bfloat16* __restrict__ out, int n4)
{
    int i = blockIdx.x * 256 + threadIdx.x;
    if (i < n4) {
        float4 v = *(const float4*)(in + (size_t)i * 4);
        __hip_bfloat16* o = out + (size_t)i * 4;
        o[0] = __float2bfloat16(v.x); o[1] = __float2bfloat16(v.y);
        o[2] = __float2bfloat16(v.z); o[3] = __float2bfloat16(v.w);
    }
}

// ---------------- W pack into B-fragment order, bf16 ----------------
__global__ __launch_bounds__(256) void pack_wp(
    const float* __restrict__ g, const float* __restrict__ r,
    __hip_bfloat16* __restrict__ Wp, int DG)
{
    int i = blockIdx.x * 256 + threadIdx.x;
    int total = (2 * DG / 16) * 2048;
    if (i >= total) return;
    int j    = i & 7;
    int lane = (i >> 3) & 63;
    int ks   = (i >> 9) & 3;
    int nt   = i >> 11;
    int k = ks * 32 + (lane >> 4) * 8 + j;
    int c = nt * 16 + (lane & 15);
    float v = (c < DG) ? g[k * DG + c] : r[k * DG + (c - DG)];
    Wp[i] = __float2bfloat16(v);
}

// ---------------- MFMA GEMM: [Hg|Hr] = A[M x 128] @ Wp, bf16 in, bf16 out ----
template<int DG>
__global__ __launch_bounds__(256) void gemm_mfma(
    const __hip_bfloat16* __restrict__ A, const __hip_bfloat16* __restrict__ Wp,
    __hip_bfloat16* __restrict__ Hg, __hip_bfloat16* __restrict__ Hr, int M)
{
    constexpr int NT2 = 2 * DG / 16;
    int tid = threadIdx.x;
    int wv = tid >> 6, lane = tid & 63;
    int m0 = blockIdx.x * 64 + wv * 16;
    int row = m0 + (lane & 15);
    int rowc = min(row, M - 1);
    int kg = lane >> 4;

    bf16x8 a[4];
    const __hip_bfloat16* ap = A + (size_t)rowc * 128 + kg * 8;
    #pragma unroll
    for (int ks = 0; ks < 4; ++ks)
        a[ks] = *(const bf16x8*)(ap + ks * 32);

    f32x4 acc[NT2] = {};
    #pragma unroll
    for (int ks = 0; ks < 4; ++ks) {
        #pragma unroll
        for (int nt = 0; nt < NT2; ++nt) {
            bf16x8 b = *(const bf16x8*)(Wp + ((size_t)(nt * 4 + ks) * 64 + lane) * 8);
            acc[nt] = __builtin_amdgcn_mfma_f32_16x16x32_bf16(a[ks], b, acc[nt], 0, 0, 0);
        }
    }

    int rbase = m0 + (lane >> 4) * 4;
    int c = lane & 15;
    #pragma unroll
    for (int nt = 0; nt < NT2; ++nt) {
        __hip_bfloat16* dst = (nt < DG / 16) ? Hg : Hr;
        int cc = (nt < DG / 16) ? (nt * 16 + c) : ((nt - DG / 16) * 16 + c);
        #pragma unroll
        for (int r = 0; r < 4; ++r) {
            int rr = rbase + r;
            if (rr < M) dst[(size_t)rr * DG + cc] = __float2bfloat16(acc[nt][r]);
        }
    }
}

// ---------------- tiny GEMM (fp32): out[M x N] = X[M x 128] @ W[128 x N] ----
__global__ __launch_bounds__(128) void small_mm(
    const float* __restrict__ X, const float* __restrict__ W,
    float* __restrict__ out, int N)
{
    __shared__ float xrow[128];
    int l = blockIdx.x, t = threadIdx.x;
    xrow[t] = X[(size_t)l * 128 + t];
    __syncthreads();
    if (t < N) {
        float o = 0.f;
        for (int k = 0; k < 128; ++k) o = fmaf(xrow[k], W[k * N + t], o);
        out[(size_t)l * N + t] = o;
    }
}

// ---------------- fused paper-side assembly (bf16 H) ----------------
template<int D, bool RELU, typename OutT>
__global__ __launch_bounds__(256) void paper_assemble(
    const __hip_bfloat16* __restrict__ Hg, const __hip_bfloat16* __restrict__ Hr,
    const int* __restrict__ rp_c, const int* __restrict__ col_c,
    const float* __restrict__ dinv,
    const int* __restrict__ rp_r, const int* __restrict__ col_r,
    const float* __restrict__ yrev,
    const float* __restrict__ gcn_b, const float* __restrict__ rev_relb,
    OutT* __restrict__ out)
{
    constexpr int NB = D / 64;  // bf16 elements per lane
    int w = (int)((blockIdx.x * 256 + threadIdx.x) >> 6);
    if (w >= N_PAPER) return;
    int lane = threadIdx.x & 63;
    int d0 = lane * NB;
    float acc[NB] = {};
    int s = rp_c[w], e = rp_c[w + 1];
    for (int j = s; j < e; ++j) {
        int src = col_c[j];
        float sc = dinv[src];
        if constexpr (NB == 2) {
            unsigned u = *(const unsigned*)(Hg + (size_t)src * D + d0);
            acc[0] = fmaf(sc, bf_lo(u), acc[0]);
            acc[1] = fmaf(sc, bf_hi(u), acc[1]);
        } else {
            acc[0] = fmaf(sc, __bfloat162float(Hg[(size_t)src * D + d0]), acc[0]);
        }
    }
    float di = dinv[w];
    float res[NB];
    #pragma unroll
    for (int b = 0; b < NB; ++b) {
        int d = d0 + b;
        res[b] = di * acc[b]
               + di * di * __bfloat162float(Hg[(size_t)w * D + d])
               + __bfloat162float(Hr[(size_t)w * D + d])
               + gcn_b[d] + rev_relb[d];
    }
    int s2 = rp_r[w], e2 = rp_r[w + 1];
    for (int j = s2; j < e2; ++j) {
        int lab = col_r[j];
        const float* yr = yrev + (size_t)lab * D;
        #pragma unroll
        for (int b = 0; b < NB; ++b) res[b] += yr[d0 + b];
    }
    #pragma unroll
    for (int b = 0; b < NB; ++b) {
        float o = 0.5f * res[b];
        if (RELU) o = fmaxf(o, 0.f);
        if constexpr (sizeof(OutT) == 2)
            out[(size_t)w * D + d0 + b] = __float2bfloat16(o);
        else
            out[(size_t)w * D + d0 + b] = o;
    }
}

// ---------------- label-side aggregation via CSR (grid: 128 labels x LSPLIT) --
__global__ __launch_bounds__(128) void label_agg(
    const __hip_bfloat16* __restrict__ Xsrc,
    const int* __restrict__ rp_l, const int* __restrict__ col_l,
    float* __restrict__ partialL)
{
    int l = blockIdx.x, sp = blockIdx.y, t = threadIdx.x;
    int s = rp_l[l], e = rp_l[l + 1];
    int n = e - s;
    int per = (n + LSPLIT - 1) / LSPLIT;
    int b = s + sp * per;
    int en = min(b + per, e);
    float acc = 0.f;
    for (int m = b; m < en; ++m)
        acc += __bfloat162float(Xsrc[(size_t)col_l[m] * 128 + t]);
    partialL[((size_t)l * LSPLIT + sp) * 128 + t] = acc;
}

// ---------------- label-side finish: sum partials + tiny GEMM ----------------
template<int DOUT, bool RELU>
__global__ __launch_bounds__(128) void label_finish(
    const float* __restrict__ partialL, const float* __restrict__ Xdst,
    const float* __restrict__ relW, const float* __restrict__ rootW,
    const float* __restrict__ relb, float* __restrict__ out)
{
    __shared__ float arow[128];
    __shared__ float xrow[128];
    int l = blockIdx.x, t = threadIdx.x;
    float a = 0.f;
    #pragma unroll
    for (int sp = 0; sp < LSPLIT; ++sp)
        a += partialL[((size_t)l * LSPLIT + sp) * 128 + t];
    arow[t] = a;
    xrow[t] = Xdst[(size_t)l * 128 + t];
    __syncthreads();
    if (t < DOUT) {
        float o = relb[t];
        for (int k = 0; k < 128; ++k)
            o = fmaf(arow[k], relW[k * DOUT + t], fmaf(xrow[k], rootW[k * DOUT + t], o));
        if (RELU) o = fmaxf(o, 0.f);
        out[(size_t)l * DOUT + t] = o;
    }
}

extern "C" void kernel_launch(void* const* d_in, const int* in_sizes, int n_in,
                              void* d_out, int out_size, void* d_ws, size_t ws_size,
                              hipStream_t stream)
{
    const float* xp          = (const float*)d_in[0];
    const float* xl          = (const float*)d_in[1];
    const int*   cs          = (const int*)d_in[2];
    const int*   cd          = (const int*)d_in[3];
    const int*   iss         = (const int*)d_in[4];
    const int*   isd         = (const int*)d_in[5];
    const float* l1_gcn_W    = (const float*)d_in[6];
    const float* l1_gcn_b    = (const float*)d_in[7];
    const float* l1_is_relW  = (const float*)d_in[8];
    const float* l1_is_relb  = (const float*)d_in[9];
    const float* l1_is_rootW = (const float*)d_in[10];
    const float* l1_rev_relW = (const float*)d_in[11];
    const float* l1_rev_relb = (const float*)d_in[12];
    const float* l1_rev_rootW= (const float*)d_in[13];
    const float* l2_gcn_W    = (const float*)d_in[14];
    const float* l2_gcn_b    = (const float*)d_in[15];
    const float* l2_is_relW  = (const float*)d_in[16];
    const float* l2_is_relb  = (const float*)d_in[17];
    const float* l2_is_rootW = (const float*)d_in[18];
    const float* l2_rev_relW = (const float*)d_in[19];
    const float* l2_rev_relb = (const float*)d_in[20];
    const float* l2_rev_rootW= (const float*)d_in[21];

    char* ws = (char*)d_ws;
    size_t off = 0;
    auto alloc = [&](size_t bytes) {
        char* p = ws + off;
        off += (bytes + 255) & ~(size_t)255;
        return p;
    };
    __hip_bfloat16* xp_bf = (__hip_bfloat16*)alloc((size_t)N_PAPER * 128 * 2);
    __hip_bfloat16* hp1   = (__hip_bfloat16*)alloc((size_t)N_PAPER * 128 * 2);
    __hip_bfloat16* Hg    = (__hip_bfloat16*)alloc((size_t)N_PAPER * 128 * 2);
    __hip_bfloat16* Hr    = (__hip_bfloat16*)alloc((size_t)N_PAPER * 128 * 2);
    unsigned* ebuf = (unsigned*)alloc((size_t)E_CITES * 4);
    int*   col_c = (int*)alloc((size_t)E_CITES * 4);
    int*   col_r = (int*)alloc((size_t)E_IS * 4);
    int*   col_l = (int*)alloc((size_t)E_IS * 4);
    int*   rp_c  = (int*)alloc((size_t)(N_PAPER + 1) * 4);
    int*   rp_r  = (int*)alloc((size_t)(N_PAPER + 1) * 4);
    int*   cur_r = (int*)alloc((size_t)(N_PAPER + 1) * 4);
    int*   rp_l  = (int*)alloc((size_t)(N_LABEL + 1) * 4);
    int*   cur_l = (int*)alloc((size_t)N_LABEL * 4);
    int*   cnt_r = (int*)alloc((size_t)N_PAPER * 4);
    int*   cnt_l = (int*)alloc((size_t)N_LABEL * 4);
    int*   bhist = (int*)alloc((size_t)NBKT * 4);
    int*   bbase = (int*)alloc((size_t)(NBKT + 1) * 4);
    int*   bcur  = (int*)alloc((size_t)NBKT * 4);
    float* dinv  = (float*)alloc((size_t)N_PAPER * 4);
    int*   bsum  = (int*)alloc((size_t)SCAN_B * 4);
    __hip_bfloat16* Wp1 = (__hip_bfloat16*)alloc((size_t)32768 * 2);
    __hip_bfloat16* Wp2 = (__hip_bfloat16*)alloc((size_t)16384 * 2);
    float* yrev1 = (float*)alloc(128 * 128 * 4);
    float* yrev2 = (float*)alloc(128 * 64 * 4);
    float* hl1   = (float*)alloc(128 * 128 * 4);
    float* partialL = (float*)alloc((size_t)N_LABEL * LSPLIT * 128 * 4);

    float* zp = (float*)d_out;                          // [100000 x 64]
    float* zl = (float*)d_out + (size_t)N_PAPER * 64;   // [128 x 64]

    hipMemsetAsync(cnt_r, 0, (size_t)N_PAPER * 4, stream);
    hipMemsetAsync(cnt_l, 0, (size_t)N_LABEL * 4, stream);
    hipMemsetAsync(bhist, 0, (size_t)NBKT * 4, stream);

    bucket_count<<<256, 256, 0, stream>>>(cd, bhist);
    count_is<<<(E_IS + 255) / 256, 256, 0, stream>>>(iss, isd, cnt_r, cnt_l);
    block_sums<<<SCAN_B, 1024, 0, stream>>>(cnt_r, bsum);
    scan_sums<<<1, 128, 0, stream>>>(bsum, cnt_l, rp_l, cur_l, bhist, bbase, bcur);
    scan_finalize<<<SCAN_B, 1024, 0, stream>>>(cnt_r, bsum, rp_r, cur_r);
    bucket_scatter<<<(E_CITES + A2_CHUNK - 1) / A2_CHUNK, 256, 0, stream>>>(cs, cd, bcur, ebuf);
    bucket_csr<<<NBKT, 1024, 0, stream>>>(ebuf, bbase, rp_c, col_c, dinv);
    scatter_is<<<(E_IS + 255) / 256, 256, 0, stream>>>(iss, isd, cur_r, col_r, cur_l, col_l);

    conv_bf16<<<(N_PAPER * 128 / 4 + 255) / 256, 256, 0, stream>>>(xp, xp_bf, N_PAPER * 128 / 4);
    pack_wp<<<(32768 + 255) / 256, 256, 0, stream>>>(l1_gcn_W, l1_rev_rootW, Wp1, 128);
    pack_wp<<<(16384 + 255) / 256, 256, 0, stream>>>(l2_gcn_W, l2_rev_rootW, Wp2, 64);
    small_mm<<<128, 128, 0, stream>>>(xl, l1_rev_relW, yrev1, 128);

    // ---- layer 1 ----
    gemm_mfma<128><<<(N_PAPER + 63) / 64, 256, 0, stream>>>(xp_bf, Wp1, Hg, Hr, N_PAPER);
    paper_assemble<128, true, __hip_bfloat16><<<(N_PAPER + 3) / 4, 256, 0, stream>>>(
        Hg, Hr, rp_c, col_c, dinv, rp_r, col_r, yrev1, l1_gcn_b, l1_rev_relb, hp1);
    label_agg<<<dim3(N_LABEL, LSPLIT), 128, 0, stream>>>(xp_bf, rp_l, col_l, partialL);
    label_finish<128, true><<<N_LABEL, 128, 0, stream>>>(
        partialL, xl, l1_is_relW, l1_is_rootW, l1_is_relb, hl1);
    small_mm<<<128, 128, 0, stream>>>(hl1, l2_rev_relW, yrev2, 64);

    // ---- layer 2 ----
    gemm_mfma<64><<<(N_PAPER + 63) / 64, 256, 0, stream>>>(hp1, Wp2, Hg, Hr, N_PAPER);
    paper_assemble<64, false, float><<<(N_PAPER + 3) / 4, 256, 0, stream>>>(
        Hg, Hr, rp_c, col_c, dinv, rp_r, col_r, yrev2, l2_gcn_b, l2_rev_relb, zp);
    label_agg<<<dim3(N_LABEL, LSPLIT), 128, 0, stream>>>(hp1, rp_l, col_l, partialL);
    label_finish<64, false><<<N_LABEL, 128, 0, stream>>>(
        partialL, hl1, l2_is_relW, l2_is_rootW, l2_is_relb, zl);
}

// Round 5
// 572.036 us; speedup vs baseline: 3.0510x; 1.2636x over previous
//
#include <hip/hip_runtime.h>
#include <hip/hip_bf16.h>

#define N_PAPER 100000
#define N_LABEL 128
#define E_CITES 1600000
#define E_IS    100000
#define SCAN_B  98   // ceil(100000/1024)
#define NBKT    98   // dst>>10 buckets
#define A2_CHUNK 2048
#define LSPLIT  8

typedef __bf16 bf16x8 __attribute__((ext_vector_type(8)));
typedef float  f32x4  __attribute__((ext_vector_type(4)));

static __device__ __forceinline__ float bf_lo(unsigned u) {
    union { unsigned u; float f; } v; v.u = u << 16; return v.f;
}
static __device__ __forceinline__ float bf_hi(unsigned u) {
    union { unsigned u; float f; } v; v.u = u & 0xffff0000u; return v.f;
}
static __device__ __forceinline__ unsigned pk_bf(float a, float b) {
    __hip_bfloat16 x = __float2bfloat16(a), y = __float2bfloat16(b);
    unsigned short ux = *(unsigned short*)&x, uy = *(unsigned short*)&y;
    return (unsigned)ux | ((unsigned)uy << 16);
}

// ---------------- cites: coarse bucket histogram ----------------
__global__ __launch_bounds__(256) void bucket_count(
    const int* __restrict__ cd, int* __restrict__ bhist)
{
    __shared__ int h[NBKT];
    int t = threadIdx.x;
    if (t < NBKT) h[t] = 0;
    __syncthreads();
    for (int i = blockIdx.x * 256 + t; i < E_CITES; i += gridDim.x * 256)
        atomicAdd(&h[cd[i] >> 10], 1);
    __syncthreads();
    if (t < NBKT && h[t]) atomicAdd(&bhist[t], h[t]);
}

// ---------------- is-edges: per-node counts ----------------
__global__ __launch_bounds__(256) void count_is(
    const int* __restrict__ iss, const int* __restrict__ isd,
    int* __restrict__ cnt_r, int* __restrict__ cnt_l)
{
    int i = blockIdx.x * 256 + threadIdx.x;
    if (i < E_IS) {
        atomicAdd(&cnt_r[iss[i]], 1);
        atomicAdd(&cnt_l[isd[i]], 1);
    }
}

// grid SCAN_B: block sums of cnt_r
__global__ __launch_bounds__(1024) void block_sums(
    const int* __restrict__ cnt_r, int* __restrict__ bsum)
{
    int i = blockIdx.x * 1024 + threadIdx.x;
    int v = (i < N_PAPER) ? cnt_r[i] : 0;
    __shared__ int sh[16];
    for (int o = 32; o; o >>= 1) v += __shfl_down(v, o);
    if ((threadIdx.x & 63) == 0) sh[threadIdx.x >> 6] = v;
    __syncthreads();
    if (threadIdx.x < 16) {
        int s = sh[threadIdx.x];
        for (int o = 8; o; o >>= 1) s += __shfl_down(s, o);
        if (threadIdx.x == 0) bsum[blockIdx.x] = s;
    }
}

// single block: scan bsum(98) + cnt_l(128) + bhist(98)
__global__ __launch_bounds__(128) void scan_sums(
    int* __restrict__ bsum, const int* __restrict__ cnt_l,
    int* __restrict__ rp_l, int* __restrict__ cur_l,
    const int* __restrict__ bhist, int* __restrict__ bbase, int* __restrict__ bcur)
{
    __shared__ int sh[3][128];
    int t = threadIdx.x;
    sh[0][t] = (t < SCAN_B) ? bsum[t] : 0;
    sh[1][t] = cnt_l[t];
    sh[2][t] = (t < NBKT) ? bhist[t] : 0;
    __syncthreads();
    for (int off = 1; off < 128; off <<= 1) {
        int v0 = (t >= off) ? sh[0][t - off] : 0;
        int v1 = (t >= off) ? sh[1][t - off] : 0;
        int v2 = (t >= off) ? sh[2][t - off] : 0;
        __syncthreads();
        sh[0][t] += v0; sh[1][t] += v1; sh[2][t] += v2;
        __syncthreads();
    }
    if (t < SCAN_B) bsum[t] = (t == 0) ? 0 : sh[0][t - 1];
    int e = (t == 0) ? 0 : sh[1][t - 1];
    rp_l[t] = e; cur_l[t] = e;
    if (t == 127) rp_l[128] = sh[1][127];
    if (t < NBKT) {
        int b = (t == 0) ? 0 : sh[2][t - 1];
        bbase[t] = b; bcur[t] = b;
        if (t == NBKT - 1) bbase[NBKT] = sh[2][t];
    }
}

// grid SCAN_B: full scan of cnt_r -> rp_r/cur_r
__global__ __launch_bounds__(1024) void scan_finalize(
    const int* __restrict__ cnt_r, const int* __restrict__ bsum,
    int* __restrict__ rp_r, int* __restrict__ cur_r)
{
    __shared__ int sh[1024];
    int t = threadIdx.x;
    int i = blockIdx.x * 1024 + t;
    int v = (i < N_PAPER) ? cnt_r[i] : 0;
    sh[t] = v;
    __syncthreads();
    for (int off = 1; off < 1024; off <<= 1) {
        int u = (t >= off) ? sh[t - off] : 0;
        __syncthreads();
        sh[t] += u;
        __syncthreads();
    }
    int excl = sh[t] - v + bsum[blockIdx.x];
    if (i < N_PAPER) {
        rp_r[i] = excl; cur_r[i] = excl;
        if (i == N_PAPER - 1) rp_r[N_PAPER] = excl + v;
    }
}

// ---------------- cites: bucketed edge scatter (packed u32) ----------------
__global__ __launch_bounds__(256) void bucket_scatter(
    const int* __restrict__ cs, const int* __restrict__ cd,
    int* __restrict__ bcur, unsigned* __restrict__ ebuf)
{
    __shared__ int sd[A2_CHUNK];
    __shared__ int ss[A2_CHUNK];
    __shared__ int h[NBKT], base[NBKT], cur[NBKT];
    int t = threadIdx.x;
    int e0 = blockIdx.x * A2_CHUNK;
    int n = min(A2_CHUNK, E_CITES - e0);
    if (t < NBKT) h[t] = 0;
    __syncthreads();
    for (int i = t; i < n; i += 256) {
        int d = cd[e0 + i], s = cs[e0 + i];
        sd[i] = d; ss[i] = s;
        atomicAdd(&h[d >> 10], 1);
    }
    __syncthreads();
    if (t < NBKT) { base[t] = atomicAdd(&bcur[t], h[t]); cur[t] = 0; }
    __syncthreads();
    for (int i = t; i < n; i += 256) {
        int b = sd[i] >> 10;
        int p = base[b] + atomicAdd(&cur[b], 1);
        ebuf[p] = ((unsigned)(sd[i] & 1023) << 17) | (unsigned)ss[i];
    }
}

// ---------------- cites: per-bucket CSR build (one block per bucket) --------
__global__ __launch_bounds__(1024) void bucket_csr(
    const unsigned* __restrict__ ebuf, const int* __restrict__ bbase,
    int* __restrict__ rp_c, int* __restrict__ col_c, float* __restrict__ dinv)
{
    __shared__ int hist[1024];
    __shared__ int sc[1024];
    int b = blockIdx.x, t = threadIdx.x;
    int s = bbase[b], e = bbase[b + 1];
    hist[t] = 0;
    __syncthreads();
    for (int i = s + t; i < e; i += 1024)
        atomicAdd(&hist[ebuf[i] >> 17], 1);
    __syncthreads();
    int v = hist[t];
    sc[t] = v;
    __syncthreads();
    for (int off = 1; off < 1024; off <<= 1) {
        int u = (t >= off) ? sc[t - off] : 0;
        __syncthreads();
        sc[t] += u;
        __syncthreads();
    }
    int excl = sc[t] - v;
    int node = b * 1024 + t;
    if (node < N_PAPER) {
        rp_c[node] = s + excl;
        dinv[node] = rsqrtf((float)v + 1.0f);
        if (node == N_PAPER - 1) rp_c[N_PAPER] = s + excl + v;
    }
    __syncthreads();
    hist[t] = s + excl;   // reuse as running cursor
    __syncthreads();
    for (int i = s + t; i < e; i += 1024) {
        unsigned u = ebuf[i];
        int p = atomicAdd(&hist[u >> 17], 1);
        col_c[p] = (int)(u & 0x1FFFFu);
    }
}

// ---------------- is-edges scatter (small) ----------------
__global__ __launch_bounds__(256) void scatter_is(
    const int* __restrict__ iss, const int* __restrict__ isd,
    int* __restrict__ cur_r, int* __restrict__ col_r,
    int* __restrict__ cur_l, int* __restrict__ col_l)
{
    int i = blockIdx.x * 256 + threadIdx.x;
    if (i < E_IS) {
        int pos = atomicAdd(&cur_r[iss[i]], 1);
        col_r[pos] = isd[i];
        int pos2 = atomicAdd(&cur_l[isd[i]], 1);
        col_l[pos2] = iss[i];
    }
}

// ---------------- fp32 -> bf16 convert (vectorized) ----------------
__global__ __launch_bounds__(256) void conv_bf16(
    const float* __restrict__ in, __hip_bfloat16* __restrict__ out, int n4)
{
    int i = blockIdx.x * 256 + threadIdx.x;
    if (i < n4) {
        float4 v = *(const float4*)(in + (size_t)i * 4);
        __hip_bfloat16* o = out + (size_t)i * 4;
        o[0] = __float2bfloat16(v.x); o[1] = __float2bfloat16(v.y);
        o[2] = __float2bfloat16(v.z); o[3] = __float2bfloat16(v.w);
    }
}

// ---------------- W pack into B-fragment order, bf16 ----------------
__global__ __launch_bounds__(256) void pack_wp(
    const float* __restrict__ g, const float* __restrict__ r,
    __hip_bfloat16* __restrict__ Wp, int DG)
{
    int i = blockIdx.x * 256 + threadIdx.x;
    int total = (2 * DG / 16) * 2048;
    if (i >= total) return;
    int j    = i & 7;
    int lane = (i >> 3) & 63;
    int ks   = (i >> 9) & 3;
    int nt   = i >> 11;
    int k = ks * 32 + (lane >> 4) * 8 + j;
    int c = nt * 16 + (lane & 15);
    float v = (c < DG) ? g[k * DG + c] : r[k * DG + (c - DG)];
    Wp[i] = __float2bfloat16(v);
}

// ---------------- MFMA GEMM: Hg = dinv.*(A@Wg), Hr = A@Wr  (bf16) ----------
template<int DG>
__global__ __launch_bounds__(256) void gemm_mfma(
    const __hip_bfloat16* __restrict__ A, const __hip_bfloat16* __restrict__ Wp,
    const float* __restrict__ dinv,
    __hip_bfloat16* __restrict__ Hg, __hip_bfloat16* __restrict__ Hr, int M)
{
    constexpr int NT2 = 2 * DG / 16;
    int tid = threadIdx.x;
    int wv = tid >> 6, lane = tid & 63;
    int m0 = blockIdx.x * 64 + wv * 16;
    int row = m0 + (lane & 15);
    int rowc = min(row, M - 1);
    int kg = lane >> 4;

    bf16x8 a[4];
    const __hip_bfloat16* ap = A + (size_t)rowc * 128 + kg * 8;
    #pragma unroll
    for (int ks = 0; ks < 4; ++ks)
        a[ks] = *(const bf16x8*)(ap + ks * 32);

    f32x4 acc[NT2] = {};
    #pragma unroll
    for (int ks = 0; ks < 4; ++ks) {
        #pragma unroll
        for (int nt = 0; nt < NT2; ++nt) {
            bf16x8 b = *(const bf16x8*)(Wp + ((size_t)(nt * 4 + ks) * 64 + lane) * 8);
            acc[nt] = __builtin_amdgcn_mfma_f32_16x16x32_bf16(a[ks], b, acc[nt], 0, 0, 0);
        }
    }

    int rbase = m0 + (lane >> 4) * 4;
    int c = lane & 15;
    float ds[4];
    #pragma unroll
    for (int r = 0; r < 4; ++r) {
        int rr = rbase + r;
        ds[r] = (rr < M) ? dinv[rr] : 1.f;
    }
    #pragma unroll
    for (int nt = 0; nt < NT2; ++nt) {
        bool isG = (nt < DG / 16);
        __hip_bfloat16* dst = isG ? Hg : Hr;
        int cc = isG ? (nt * 16 + c) : ((nt - DG / 16) * 16 + c);
        #pragma unroll
        for (int r = 0; r < 4; ++r) {
            int rr = rbase + r;
            float v = isG ? acc[nt][r] * ds[r] : acc[nt][r];
            if (rr < M) dst[(size_t)rr * DG + cc] = __float2bfloat16(v);
        }
    }
}

// ---------------- tiny GEMM (fp32): out[M x N] = X[M x 128] @ W[128 x N] ----
__global__ __launch_bounds__(128) void small_mm(
    const float* __restrict__ X, const float* __restrict__ W,
    float* __restrict__ out, int N)
{
    __shared__ float xrow[128];
    int l = blockIdx.x, t = threadIdx.x;
    xrow[t] = X[(size_t)l * 128 + t];
    __syncthreads();
    if (t < N) {
        float o = 0.f;
        for (int k = 0; k < 128; ++k) o = fmaf(xrow[k], W[k * N + t], o);
        out[(size_t)l * N + t] = o;
    }
}

// ---------------- fused paper-side assembly (bf16 H, Hg pre-scaled) ---------
// out = [relu] 0.5*( di*(sum_e Hg'[src] + Hg'[w]) + Hr[w] + gcn_b + rev_relb
//                    + sum_{is} yrev[lab] )
// wave per node; 4x16-lane groups process 4 edges concurrently, 16B/lane.
template<int D, bool RELU, typename OutT>
__global__ __launch_bounds__(256) void paper_assemble(
    const __hip_bfloat16* __restrict__ Hg, const __hip_bfloat16* __restrict__ Hr,
    const int* __restrict__ rp_c, const int* __restrict__ col_c,
    const float* __restrict__ dinv,
    const int* __restrict__ rp_r, const int* __restrict__ col_r,
    const float* __restrict__ yrev,
    const float* __restrict__ gcn_b, const float* __restrict__ rev_relb,
    OutT* __restrict__ out)
{
    constexpr int NB = D / 16;  // dims per lane: 8 (D=128) or 4 (D=64)
    int w = (int)((blockIdx.x * 256 + threadIdx.x) >> 6);
    if (w >= N_PAPER) return;
    int lane = threadIdx.x & 63;
    int grp = lane >> 4, sub = lane & 15;
    int d0 = sub * NB;
    float acc[NB] = {};
    int s = rp_c[w], e = rp_c[w + 1];
    for (int j = s + grp; j < e; j += 4) {
        int src = col_c[j];
        const __hip_bfloat16* p = Hg + (size_t)src * D + d0;
        if constexpr (NB == 8) {
            uint4 u = *(const uint4*)p;
            acc[0] += bf_lo(u.x); acc[1] += bf_hi(u.x);
            acc[2] += bf_lo(u.y); acc[3] += bf_hi(u.y);
            acc[4] += bf_lo(u.z); acc[5] += bf_hi(u.z);
            acc[6] += bf_lo(u.w); acc[7] += bf_hi(u.w);
        } else {
            uint2 u = *(const uint2*)p;
            acc[0] += bf_lo(u.x); acc[1] += bf_hi(u.x);
            acc[2] += bf_lo(u.y); acc[3] += bf_hi(u.y);
        }
    }
    #pragma unroll
    for (int k = 0; k < NB; ++k) {
        acc[k] += __shfl_xor(acc[k], 16);
        acc[k] += __shfl_xor(acc[k], 32);
    }
    if (grp != 0) return;

    float di = dinv[w];
    float res[NB];
    const __hip_bfloat16* hg = Hg + (size_t)w * D + d0;
    const __hip_bfloat16* hr = Hr + (size_t)w * D + d0;
    if constexpr (NB == 8) {
        uint4 ug = *(const uint4*)hg;
        uint4 ur = *(const uint4*)hr;
        float sg[8] = { bf_lo(ug.x), bf_hi(ug.x), bf_lo(ug.y), bf_hi(ug.y),
                        bf_lo(ug.z), bf_hi(ug.z), bf_lo(ug.w), bf_hi(ug.w) };
        float sr[8] = { bf_lo(ur.x), bf_hi(ur.x), bf_lo(ur.y), bf_hi(ur.y),
                        bf_lo(ur.z), bf_hi(ur.z), bf_lo(ur.w), bf_hi(ur.w) };
        #pragma unroll
        for (int k = 0; k < 8; ++k)
            res[k] = di * (acc[k] + sg[k]) + sr[k] + gcn_b[d0 + k] + rev_relb[d0 + k];
    } else {
        uint2 ug = *(const uint2*)hg;
        uint2 ur = *(const uint2*)hr;
        float sg[4] = { bf_lo(ug.x), bf_hi(ug.x), bf_lo(ug.y), bf_hi(ug.y) };
        float sr[4] = { bf_lo(ur.x), bf_hi(ur.x), bf_lo(ur.y), bf_hi(ur.y) };
        #pragma unroll
        for (int k = 0; k < 4; ++k)
            res[k] = di * (acc[k] + sg[k]) + sr[k] + gcn_b[d0 + k] + rev_relb[d0 + k];
    }
    int s2 = rp_r[w], e2 = rp_r[w + 1];
    for (int j = s2; j < e2; ++j) {
        const float* yr = yrev + (size_t)col_r[j] * D + d0;
        #pragma unroll
        for (int k = 0; k < NB; ++k) res[k] += yr[k];
    }
    #pragma unroll
    for (int k = 0; k < NB; ++k) {
        res[k] *= 0.5f;
        if (RELU) res[k] = fmaxf(res[k], 0.f);
    }
    if constexpr (sizeof(OutT) == 2) {
        if constexpr (NB == 8) {
            uint4 o = make_uint4(pk_bf(res[0], res[1]), pk_bf(res[2], res[3]),
                                 pk_bf(res[4], res[5]), pk_bf(res[6], res[7]));
            *(uint4*)(out + (size_t)w * D + d0) = o;
        } else {
            uint2 o = make_uint2(pk_bf(res[0], res[1]), pk_bf(res[2], res[3]));
            *(uint2*)(out + (size_t)w * D + d0) = o;
        }
    } else {
        if constexpr (NB == 8) {
            *(float4*)((float*)out + (size_t)w * D + d0) =
                make_float4(res[0], res[1], res[2], res[3]);
            *(float4*)((float*)out + (size_t)w * D + d0 + 4) =
                make_float4(res[4], res[5], res[6], res[7]);
        } else {
            *(float4*)((float*)out + (size_t)w * D + d0) =
                make_float4(res[0], res[1], res[2], res[3]);
        }
    }
}

// ---------------- label-side aggregation via CSR (grid: 128 labels x LSPLIT) --
__global__ __launch_bounds__(128) void label_agg(
    const __hip_bfloat16* __restrict__ Xsrc,
    const int* __restrict__ rp_l, const int* __restrict__ col_l,
    float* __restrict__ partialL)
{
    int l = blockIdx.x, sp = blockIdx.y, t = threadIdx.x;
    int s = rp_l[l], e = rp_l[l + 1];
    int n = e - s;
    int per = (n + LSPLIT - 1) / LSPLIT;
    int b = s + sp * per;
    int en = min(b + per, e);
    float acc = 0.f;
    for (int m = b; m < en; ++m)
        acc += __bfloat162float(Xsrc[(size_t)col_l[m] * 128 + t]);
    partialL[((size_t)l * LSPLIT + sp) * 128 + t] = acc;
}

// ---------------- label-side finish: sum partials + tiny GEMM ----------------
template<int DOUT, bool RELU>
__global__ __launch_bounds__(128) void label_finish(
    const float* __restrict__ partialL, const float* __restrict__ Xdst,
    const float* __restrict__ relW, const float* __restrict__ rootW,
    const float* __restrict__ relb, float* __restrict__ out)
{
    __shared__ float arow[128];
    __shared__ float xrow[128];
    int l = blockIdx.x, t = threadIdx.x;
    float a = 0.f;
    #pragma unroll
    for (int sp = 0; sp < LSPLIT; ++sp)
        a += partialL[((size_t)l * LSPLIT + sp) * 128 + t];
    arow[t] = a;
    xrow[t] = Xdst[(size_t)l * 128 + t];
    __syncthreads();
    if (t < DOUT) {
        float o = relb[t];
        for (int k = 0; k < 128; ++k)
            o = fmaf(arow[k], relW[k * DOUT + t], fmaf(xrow[k], rootW[k * DOUT + t], o));
        if (RELU) o = fmaxf(o, 0.f);
        out[(size_t)l * DOUT + t] = o;
    }
}

extern "C" void kernel_launch(void* const* d_in, const int* in_sizes, int n_in,
                              void* d_out, int out_size, void* d_ws, size_t ws_size,
                              hipStream_t stream)
{
    const float* xp          = (const float*)d_in[0];
    const float* xl          = (const float*)d_in[1];
    const int*   cs          = (const int*)d_in[2];
    const int*   cd          = (const int*)d_in[3];
    const int*   iss         = (const int*)d_in[4];
    const int*   isd         = (const int*)d_in[5];
    const float* l1_gcn_W    = (const float*)d_in[6];
    const float* l1_gcn_b    = (const float*)d_in[7];
    const float* l1_is_relW  = (const float*)d_in[8];
    const float* l1_is_relb  = (const float*)d_in[9];
    const float* l1_is_rootW = (const float*)d_in[10];
    const float* l1_rev_relW = (const float*)d_in[11];
    const float* l1_rev_relb = (const float*)d_in[12];
    const float* l1_rev_rootW= (const float*)d_in[13];
    const float* l2_gcn_W    = (const float*)d_in[14];
    const float* l2_gcn_b    = (const float*)d_in[15];
    const float* l2_is_relW  = (const float*)d_in[16];
    const float* l2_is_relb  = (const float*)d_in[17];
    const float* l2_is_rootW = (const float*)d_in[18];
    const float* l2_rev_relW = (const float*)d_in[19];
    const float* l2_rev_relb = (const float*)d_in[20];
    const float* l2_rev_rootW= (const float*)d_in[21];

    char* ws = (char*)d_ws;
    size_t off = 0;
    auto alloc = [&](size_t bytes) {
        char* p = ws + off;
        off += (bytes + 255) & ~(size_t)255;
        return p;
    };
    __hip_bfloat16* xp_bf = (__hip_bfloat16*)alloc((size_t)N_PAPER * 128 * 2);
    __hip_bfloat16* hp1   = (__hip_bfloat16*)alloc((size_t)N_PAPER * 128 * 2);
    __hip_bfloat16* Hg    = (__hip_bfloat16*)alloc((size_t)N_PAPER * 128 * 2);
    __hip_bfloat16* Hr    = (__hip_bfloat16*)alloc((size_t)N_PAPER * 128 * 2);
    unsigned* ebuf = (unsigned*)alloc((size_t)E_CITES * 4);
    int*   col_c = (int*)alloc((size_t)E_CITES * 4);
    int*   col_r = (int*)alloc((size_t)E_IS * 4);
    int*   col_l = (int*)alloc((size_t)E_IS * 4);
    int*   rp_c  = (int*)alloc((size_t)(N_PAPER + 1) * 4);
    int*   rp_r  = (int*)alloc((size_t)(N_PAPER + 1) * 4);
    int*   cur_r = (int*)alloc((size_t)(N_PAPER + 1) * 4);
    int*   rp_l  = (int*)alloc((size_t)(N_LABEL + 1) * 4);
    int*   cur_l = (int*)alloc((size_t)N_LABEL * 4);
    int*   cnt_r = (int*)alloc((size_t)N_PAPER * 4);
    int*   cnt_l = (int*)alloc((size_t)N_LABEL * 4);
    int*   bhist = (int*)alloc((size_t)NBKT * 4);
    int*   bbase = (int*)alloc((size_t)(NBKT + 1) * 4);
    int*   bcur  = (int*)alloc((size_t)NBKT * 4);
    float* dinv  = (float*)alloc((size_t)N_PAPER * 4);
    int*   bsum  = (int*)alloc((size_t)SCAN_B * 4);
    __hip_bfloat16* Wp1 = (__hip_bfloat16*)alloc((size_t)32768 * 2);
    __hip_bfloat16* Wp2 = (__hip_bfloat16*)alloc((size_t)16384 * 2);
    float* yrev1 = (float*)alloc(128 * 128 * 4);
    float* yrev2 = (float*)alloc(128 * 64 * 4);
    float* hl1   = (float*)alloc(128 * 128 * 4);
    float* partialL = (float*)alloc((size_t)N_LABEL * LSPLIT * 128 * 4);

    float* zp = (float*)d_out;                          // [100000 x 64]
    float* zl = (float*)d_out + (size_t)N_PAPER * 64;   // [128 x 64]

    hipMemsetAsync(cnt_r, 0, (size_t)N_PAPER * 4, stream);
    hipMemsetAsync(cnt_l, 0, (size_t)N_LABEL * 4, stream);
    hipMemsetAsync(bhist, 0, (size_t)NBKT * 4, stream);

    bucket_count<<<256, 256, 0, stream>>>(cd, bhist);
    count_is<<<(E_IS + 255) / 256, 256, 0, stream>>>(iss, isd, cnt_r, cnt_l);
    block_sums<<<SCAN_B, 1024, 0, stream>>>(cnt_r, bsum);
    scan_sums<<<1, 128, 0, stream>>>(bsum, cnt_l, rp_l, cur_l, bhist, bbase, bcur);
    scan_finalize<<<SCAN_B, 1024, 0, stream>>>(cnt_r, bsum, rp_r, cur_r);
    bucket_scatter<<<(E_CITES + A2_CHUNK - 1) / A2_CHUNK, 256, 0, stream>>>(cs, cd, bcur, ebuf);
    bucket_csr<<<NBKT, 1024, 0, stream>>>(ebuf, bbase, rp_c, col_c, dinv);
    scatter_is<<<(E_IS + 255) / 256, 256, 0, stream>>>(iss, isd, cur_r, col_r, cur_l, col_l);

    conv_bf16<<<(N_PAPER * 128 / 4 + 255) / 256, 256, 0, stream>>>(xp, xp_bf, N_PAPER * 128 / 4);
    pack_wp<<<(32768 + 255) / 256, 256, 0, stream>>>(l1_gcn_W, l1_rev_rootW, Wp1, 128);
    pack_wp<<<(16384 + 255) / 256, 256, 0, stream>>>(l2_gcn_W, l2_rev_rootW, Wp2, 64);
    small_mm<<<128, 128, 0, stream>>>(xl, l1_rev_relW, yrev1, 128);

    // ---- layer 1 ----
    gemm_mfma<128><<<(N_PAPER + 63) / 64, 256, 0, stream>>>(xp_bf, Wp1, dinv, Hg, Hr, N_PAPER);
    paper_assemble<128, true, __hip_bfloat16><<<(N_PAPER + 3) / 4, 256, 0, stream>>>(
        Hg, Hr, rp_c, col_c, dinv, rp_r, col_r, yrev1, l1_gcn_b, l1_rev_relb, hp1);
    label_agg<<<dim3(N_LABEL, LSPLIT), 128, 0, stream>>>(xp_bf, rp_l, col_l, partialL);
    label_finish<128, true><<<N_LABEL, 128, 0, stream>>>(
        partialL, xl, l1_is_relW, l1_is_rootW, l1_is_relb, hl1);
    small_mm<<<128, 128, 0, stream>>>(hl1, l2_rev_relW, yrev2, 64);

    // ---- layer 2 ----
    gemm_mfma<64><<<(N_PAPER + 63) / 64, 256, 0, stream>>>(hp1, Wp2, dinv, Hg, Hr, N_PAPER);
    paper_assemble<64, false, float><<<(N_PAPER + 3) / 4, 256, 0, stream>>>(
        Hg, Hr, rp_c, col_c, dinv, rp_r, col_r, yrev2, l2_gcn_b, l2_rev_relb, zp);
    label_agg<<<dim3(N_LABEL, LSPLIT), 128, 0, stream>>>(hp1, rp_l, col_l, partialL);
    label_finish<64, false><<<N_LABEL, 128, 0, stream>>>(
        partialL, hl1, l2_is_relW, l2_is_rootW, l2_is_relb, zl);
}

// Round 6
// 415.269 us; speedup vs baseline: 4.2028x; 1.3775x over previous
//
#include <hip/hip_runtime.h>
#include <hip/hip_bf16.h>

#define N_PAPER 100000
#define N_LABEL 128
#define E_CITES 1600000
#define E_IS    100000
#define NBKT    98   // node>>10 buckets
#define A2_CHUNK 2048
#define LSPLIT  8

typedef __bf16 bf16x8 __attribute__((ext_vector_type(8)));
typedef float  f32x4  __attribute__((ext_vector_type(4)));

static __device__ __forceinline__ float bf_lo(unsigned u) {
    union { unsigned u; float f; } v; v.u = u << 16; return v.f;
}
static __device__ __forceinline__ float bf_hi(unsigned u) {
    union { unsigned u; float f; } v; v.u = u & 0xffff0000u; return v.f;
}
static __device__ __forceinline__ unsigned pk_bf(float a, float b) {
    __hip_bfloat16 x = __float2bfloat16(a), y = __float2bfloat16(b);
    unsigned short ux = *(unsigned short*)&x, uy = *(unsigned short*)&y;
    return (unsigned)ux | ((unsigned)uy << 16);
}

// ---------------- generic bucket histogram ----------------
template<int NB, int SHIFT>
__global__ __launch_bounds__(256) void bucket_count_k(
    const int* __restrict__ key, int E, int* __restrict__ bhist)
{
    __shared__ int h[NB];
    int t = threadIdx.x;
    for (int i = t; i < NB; i += 256) h[i] = 0;
    __syncthreads();
    for (int i = blockIdx.x * 256 + t; i < E; i += gridDim.x * 256)
        atomicAdd(&h[key[i] >> SHIFT], 1);
    __syncthreads();
    for (int i = t; i < NB; i += 256) if (h[i]) atomicAdd(&bhist[i], h[i]);
}

// single block: exclusive-scan three histograms (cites 98, rev 98, label 128)
__global__ __launch_bounds__(128) void scan_sums(
    const int* __restrict__ bhist_c, int* __restrict__ bbase_c, int* __restrict__ bcur_c,
    const int* __restrict__ bhist_r, int* __restrict__ bbase_r, int* __restrict__ bcur_r,
    const int* __restrict__ bhist_l, int* __restrict__ rp_l, int* __restrict__ bcur_l)
{
    __shared__ int sh[3][128];
    int t = threadIdx.x;
    sh[0][t] = (t < NBKT) ? bhist_c[t] : 0;
    sh[1][t] = (t < NBKT) ? bhist_r[t] : 0;
    sh[2][t] = bhist_l[t];
    __syncthreads();
    for (int off = 1; off < 128; off <<= 1) {
        int v0 = (t >= off) ? sh[0][t - off] : 0;
        int v1 = (t >= off) ? sh[1][t - off] : 0;
        int v2 = (t >= off) ? sh[2][t - off] : 0;
        __syncthreads();
        sh[0][t] += v0; sh[1][t] += v1; sh[2][t] += v2;
        __syncthreads();
    }
    if (t < NBKT) {
        int b = (t == 0) ? 0 : sh[0][t - 1];
        bbase_c[t] = b; bcur_c[t] = b;
        if (t == NBKT - 1) bbase_c[NBKT] = sh[0][t];
        int b2 = (t == 0) ? 0 : sh[1][t - 1];
        bbase_r[t] = b2; bcur_r[t] = b2;
        if (t == NBKT - 1) bbase_r[NBKT] = sh[1][t];
    }
    int b3 = (t == 0) ? 0 : sh[2][t - 1];
    rp_l[t] = b3; bcur_l[t] = b3;
    if (t == 127) rp_l[128] = sh[2][127];
}

// ---------------- generic bucketed edge scatter (packed u32) ----------------
// ebuf[p] = ((key & 1023) << 17) | val   (val < 2^17)
template<int NB, int SHIFT>
__global__ __launch_bounds__(256) void bucket_scatter_k(
    const int* __restrict__ key, const int* __restrict__ val, int E,
    int* __restrict__ bcur, unsigned* __restrict__ ebuf)
{
    __shared__ int sk[A2_CHUNK], sv[A2_CHUNK];
    __shared__ int h[NB], base[NB], cur[NB];
    int t = threadIdx.x;
    int e0 = blockIdx.x * A2_CHUNK;
    int n = min(A2_CHUNK, E - e0);
    for (int i = t; i < NB; i += 256) h[i] = 0;
    __syncthreads();
    for (int i = t; i < n; i += 256) {
        int k = key[e0 + i], v = val[e0 + i];
        sk[i] = k; sv[i] = v;
        atomicAdd(&h[k >> SHIFT], 1);
    }
    __syncthreads();
    for (int i = t; i < NB; i += 256) { base[i] = atomicAdd(&bcur[i], h[i]); cur[i] = 0; }
    __syncthreads();
    for (int i = t; i < n; i += 256) {
        int b = sk[i] >> SHIFT;
        int p = base[b] + atomicAdd(&cur[b], 1);
        ebuf[p] = ((unsigned)(sk[i] & 1023) << 17) | (unsigned)sv[i];
    }
}

// ---------------- per-bucket CSR build (one block per 1024-node bucket) -----
template<bool DINV>
__global__ __launch_bounds__(1024) void bucket_csr(
    const unsigned* __restrict__ ebuf, const int* __restrict__ bbase,
    int* __restrict__ rp, int* __restrict__ col, float* __restrict__ dinv)
{
    __shared__ int hist[1024];
    __shared__ int sc[1024];
    int b = blockIdx.x, t = threadIdx.x;
    int s = bbase[b], e = bbase[b + 1];
    hist[t] = 0;
    __syncthreads();
    for (int i = s + t; i < e; i += 1024)
        atomicAdd(&hist[ebuf[i] >> 17], 1);
    __syncthreads();
    int v = hist[t];
    sc[t] = v;
    __syncthreads();
    for (int off = 1; off < 1024; off <<= 1) {
        int u = (t >= off) ? sc[t - off] : 0;
        __syncthreads();
        sc[t] += u;
        __syncthreads();
    }
    int excl = sc[t] - v;
    int node = b * 1024 + t;
    if (node < N_PAPER) {
        rp[node] = s + excl;
        if (DINV) dinv[node] = rsqrtf((float)v + 1.0f);
        if (node == N_PAPER - 1) rp[N_PAPER] = s + excl + v;
    }
    __syncthreads();
    hist[t] = s + excl;   // reuse as running cursor
    __syncthreads();
    for (int i = s + t; i < e; i += 1024) {
        unsigned u = ebuf[i];
        int p = atomicAdd(&hist[u >> 17], 1);
        col[p] = (int)(u & 0x1FFFFu);
    }
}

// ---------------- fp32 -> bf16 convert (vectorized) ----------------
__global__ __launch_bounds__(256) void conv_bf16(
    const float* __restrict__ in, __hip_bfloat16* __restrict__ out, int n4)
{
    int i = blockIdx.x * 256 + threadIdx.x;
    if (i < n4) {
        float4 v = *(const float4*)(in + (size_t)i * 4);
        __hip_bfloat16* o = out + (size_t)i * 4;
        o[0] = __float2bfloat16(v.x); o[1] = __float2bfloat16(v.y);
        o[2] = __float2bfloat16(v.z); o[3] = __float2bfloat16(v.w);
    }
}

// ---------------- W pack into B-fragment order, bf16 ----------------
__global__ __launch_bounds__(256) void pack_wp(
    const float* __restrict__ g, const float* __restrict__ r,
    __hip_bfloat16* __restrict__ Wp, int DG)
{
    int i = blockIdx.x * 256 + threadIdx.x;
    int total = (2 * DG / 16) * 2048;
    if (i >= total) return;
    int j    = i & 7;
    int lane = (i >> 3) & 63;
    int ks   = (i >> 9) & 3;
    int nt   = i >> 11;
    int k = ks * 32 + (lane >> 4) * 8 + j;
    int c = nt * 16 + (lane & 15);
    float v = (c < DG) ? g[k * DG + c] : r[k * DG + (c - DG)];
    Wp[i] = __float2bfloat16(v);
}

// ---------------- MFMA GEMM: Hg = dinv.*(A@Wg), Hr = A@Wr  (bf16) ----------
template<int DG>
__global__ __launch_bounds__(256) void gemm_mfma(
    const __hip_bfloat16* __restrict__ A, const __hip_bfloat16* __restrict__ Wp,
    const float* __restrict__ dinv,
    __hip_bfloat16* __restrict__ Hg, __hip_bfloat16* __restrict__ Hr, int M)
{
    constexpr int NT2 = 2 * DG / 16;
    int tid = threadIdx.x;
    int wv = tid >> 6, lane = tid & 63;
    int m0 = blockIdx.x * 64 + wv * 16;
    int row = m0 + (lane & 15);
    int rowc = min(row, M - 1);
    int kg = lane >> 4;

    bf16x8 a[4];
    const __hip_bfloat16* ap = A + (size_t)rowc * 128 + kg * 8;
    #pragma unroll
    for (int ks = 0; ks < 4; ++ks)
        a[ks] = *(const bf16x8*)(ap + ks * 32);

    f32x4 acc[NT2] = {};
    #pragma unroll
    for (int ks = 0; ks < 4; ++ks) {
        #pragma unroll
        for (int nt = 0; nt < NT2; ++nt) {
            bf16x8 b = *(const bf16x8*)(Wp + ((size_t)(nt * 4 + ks) * 64 + lane) * 8);
            acc[nt] = __builtin_amdgcn_mfma_f32_16x16x32_bf16(a[ks], b, acc[nt], 0, 0, 0);
        }
    }

    int rbase = m0 + (lane >> 4) * 4;
    int c = lane & 15;
    float ds[4];
    #pragma unroll
    for (int r = 0; r < 4; ++r) {
        int rr = rbase + r;
        ds[r] = (rr < M) ? dinv[rr] : 1.f;
    }
    #pragma unroll
    for (int nt = 0; nt < NT2; ++nt) {
        bool isG = (nt < DG / 16);
        __hip_bfloat16* dst = isG ? Hg : Hr;
        int cc = isG ? (nt * 16 + c) : ((nt - DG / 16) * 16 + c);
        #pragma unroll
        for (int r = 0; r < 4; ++r) {
            int rr = rbase + r;
            float v = isG ? acc[nt][r] * ds[r] : acc[nt][r];
            if (rr < M) dst[(size_t)rr * DG + cc] = __float2bfloat16(v);
        }
    }
}

// ---------------- tiny GEMM (fp32): out[M x N] = X[M x 128] @ W[128 x N] ----
__global__ __launch_bounds__(128) void small_mm(
    const float* __restrict__ X, const float* __restrict__ W,
    float* __restrict__ out, int N)
{
    __shared__ float xrow[128];
    int l = blockIdx.x, t = threadIdx.x;
    xrow[t] = X[(size_t)l * 128 + t];
    __syncthreads();
    if (t < N) {
        float o = 0.f;
        for (int k = 0; k < 128; ++k) o = fmaf(xrow[k], W[k * N + t], o);
        out[(size_t)l * N + t] = o;
    }
}

// ---------------- fused paper-side assembly (bf16 H, Hg pre-scaled) ---------
template<int D, bool RELU, typename OutT>
__global__ __launch_bounds__(256) void paper_assemble(
    const __hip_bfloat16* __restrict__ Hg, const __hip_bfloat16* __restrict__ Hr,
    const int* __restrict__ rp_c, const int* __restrict__ col_c,
    const float* __restrict__ dinv,
    const int* __restrict__ rp_r, const int* __restrict__ col_r,
    const float* __restrict__ yrev,
    const float* __restrict__ gcn_b, const float* __restrict__ rev_relb,
    OutT* __restrict__ out)
{
    constexpr int NB = D / 16;  // dims per lane: 8 (D=128) or 4 (D=64)
    int w = (int)((blockIdx.x * 256 + threadIdx.x) >> 6);
    if (w >= N_PAPER) return;
    int lane = threadIdx.x & 63;
    int grp = lane >> 4, sub = lane & 15;
    int d0 = sub * NB;
    float acc[NB] = {};
    int s = rp_c[w], e = rp_c[w + 1];
    for (int j = s + grp; j < e; j += 4) {
        int src = col_c[j];
        const __hip_bfloat16* p = Hg + (size_t)src * D + d0;
        if constexpr (NB == 8) {
            uint4 u = *(const uint4*)p;
            acc[0] += bf_lo(u.x); acc[1] += bf_hi(u.x);
            acc[2] += bf_lo(u.y); acc[3] += bf_hi(u.y);
            acc[4] += bf_lo(u.z); acc[5] += bf_hi(u.z);
            acc[6] += bf_lo(u.w); acc[7] += bf_hi(u.w);
        } else {
            uint2 u = *(const uint2*)p;
            acc[0] += bf_lo(u.x); acc[1] += bf_hi(u.x);
            acc[2] += bf_lo(u.y); acc[3] += bf_hi(u.y);
        }
    }
    #pragma unroll
    for (int k = 0; k < NB; ++k) {
        acc[k] += __shfl_xor(acc[k], 16);
        acc[k] += __shfl_xor(acc[k], 32);
    }
    if (grp != 0) return;

    float di = dinv[w];
    float res[NB];
    const __hip_bfloat16* hg = Hg + (size_t)w * D + d0;
    const __hip_bfloat16* hr = Hr + (size_t)w * D + d0;
    if constexpr (NB == 8) {
        uint4 ug = *(const uint4*)hg;
        uint4 ur = *(const uint4*)hr;
        float sg[8] = { bf_lo(ug.x), bf_hi(ug.x), bf_lo(ug.y), bf_hi(ug.y),
                        bf_lo(ug.z), bf_hi(ug.z), bf_lo(ug.w), bf_hi(ug.w) };
        float sr[8] = { bf_lo(ur.x), bf_hi(ur.x), bf_lo(ur.y), bf_hi(ur.y),
                        bf_lo(ur.z), bf_hi(ur.z), bf_lo(ur.w), bf_hi(ur.w) };
        #pragma unroll
        for (int k = 0; k < 8; ++k)
            res[k] = di * (acc[k] + sg[k]) + sr[k] + gcn_b[d0 + k] + rev_relb[d0 + k];
    } else {
        uint2 ug = *(const uint2*)hg;
        uint2 ur = *(const uint2*)hr;
        float sg[4] = { bf_lo(ug.x), bf_hi(ug.x), bf_lo(ug.y), bf_hi(ug.y) };
        float sr[4] = { bf_lo(ur.x), bf_hi(ur.x), bf_lo(ur.y), bf_hi(ur.y) };
        #pragma unroll
        for (int k = 0; k < 4; ++k)
            res[k] = di * (acc[k] + sg[k]) + sr[k] + gcn_b[d0 + k] + rev_relb[d0 + k];
    }
    int s2 = rp_r[w], e2 = rp_r[w + 1];
    for (int j = s2; j < e2; ++j) {
        const float* yr = yrev + (size_t)col_r[j] * D + d0;
        #pragma unroll
        for (int k = 0; k < NB; ++k) res[k] += yr[k];
    }
    #pragma unroll
    for (int k = 0; k < NB; ++k) {
        res[k] *= 0.5f;
        if (RELU) res[k] = fmaxf(res[k], 0.f);
    }
    if constexpr (sizeof(OutT) == 2) {
        if constexpr (NB == 8) {
            uint4 o = make_uint4(pk_bf(res[0], res[1]), pk_bf(res[2], res[3]),
                                 pk_bf(res[4], res[5]), pk_bf(res[6], res[7]));
            *(uint4*)(out + (size_t)w * D + d0) = o;
        } else {
            uint2 o = make_uint2(pk_bf(res[0], res[1]), pk_bf(res[2], res[3]));
            *(uint2*)(out + (size_t)w * D + d0) = o;
        }
    } else {
        if constexpr (NB == 8) {
            *(float4*)((float*)out + (size_t)w * D + d0) =
                make_float4(res[0], res[1], res[2], res[3]);
            *(float4*)((float*)out + (size_t)w * D + d0 + 4) =
                make_float4(res[4], res[5], res[6], res[7]);
        } else {
            *(float4*)((float*)out + (size_t)w * D + d0) =
                make_float4(res[0], res[1], res[2], res[3]);
        }
    }
}

// ---------------- label-side aggregation (grid: 128 labels x LSPLIT) --------
__global__ __launch_bounds__(128) void label_agg(
    const __hip_bfloat16* __restrict__ Xsrc,
    const int* __restrict__ rp_l, const unsigned* __restrict__ ebuf_l,
    float* __restrict__ partialL)
{
    int l = blockIdx.x, sp = blockIdx.y, t = threadIdx.x;
    int s = rp_l[l], e = rp_l[l + 1];
    int n = e - s;
    int per = (n + LSPLIT - 1) / LSPLIT;
    int b = s + sp * per;
    int en = min(b + per, e);
    float acc = 0.f;
    for (int m = b; m < en; ++m)
        acc += __bfloat162float(Xsrc[(size_t)(ebuf_l[m] & 0x1FFFFu) * 128 + t]);
    partialL[((size_t)l * LSPLIT + sp) * 128 + t] = acc;
}

// ---------------- label-side finish: sum partials + tiny GEMM ----------------
template<int DOUT, bool RELU>
__global__ __launch_bounds__(128) void label_finish(
    const float* __restrict__ partialL, const float* __restrict__ Xdst,
    const float* __restrict__ relW, const float* __restrict__ rootW,
    const float* __restrict__ relb, float* __restrict__ out)
{
    __shared__ float arow[128];
    __shared__ float xrow[128];
    int l = blockIdx.x, t = threadIdx.x;
    float a = 0.f;
    #pragma unroll
    for (int sp = 0; sp < LSPLIT; ++sp)
        a += partialL[((size_t)l * LSPLIT + sp) * 128 + t];
    arow[t] = a;
    xrow[t] = Xdst[(size_t)l * 128 + t];
    __syncthreads();
    if (t < DOUT) {
        float o = relb[t];
        for (int k = 0; k < 128; ++k)
            o = fmaf(arow[k], relW[k * DOUT + t], fmaf(xrow[k], rootW[k * DOUT + t], o));
        if (RELU) o = fmaxf(o, 0.f);
        out[(size_t)l * DOUT + t] = o;
    }
}

extern "C" void kernel_launch(void* const* d_in, const int* in_sizes, int n_in,
                              void* d_out, int out_size, void* d_ws, size_t ws_size,
                              hipStream_t stream)
{
    const float* xp          = (const float*)d_in[0];
    const float* xl          = (const float*)d_in[1];
    const int*   cs          = (const int*)d_in[2];
    const int*   cd          = (const int*)d_in[3];
    const int*   iss         = (const int*)d_in[4];
    const int*   isd         = (const int*)d_in[5];
    const float* l1_gcn_W    = (const float*)d_in[6];
    const float* l1_gcn_b    = (const float*)d_in[7];
    const float* l1_is_relW  = (const float*)d_in[8];
    const float* l1_is_relb  = (const float*)d_in[9];
    const float* l1_is_rootW = (const float*)d_in[10];
    const float* l1_rev_relW = (const float*)d_in[11];
    const float* l1_rev_relb = (const float*)d_in[12];
    const float* l1_rev_rootW= (const float*)d_in[13];
    const float* l2_gcn_W    = (const float*)d_in[14];
    const float* l2_gcn_b    = (const float*)d_in[15];
    const float* l2_is_relW  = (const float*)d_in[16];
    const float* l2_is_relb  = (const float*)d_in[17];
    const float* l2_is_rootW = (const float*)d_in[18];
    const float* l2_rev_relW = (const float*)d_in[19];
    const float* l2_rev_relb = (const float*)d_in[20];
    const float* l2_rev_rootW= (const float*)d_in[21];

    char* ws = (char*)d_ws;
    size_t off = 0;
    auto alloc = [&](size_t bytes) {
        char* p = ws + off;
        off += (bytes + 255) & ~(size_t)255;
        return p;
    };
    __hip_bfloat16* xp_bf = (__hip_bfloat16*)alloc((size_t)N_PAPER * 128 * 2);
    __hip_bfloat16* hp1   = (__hip_bfloat16*)alloc((size_t)N_PAPER * 128 * 2);
    __hip_bfloat16* Hg    = (__hip_bfloat16*)alloc((size_t)N_PAPER * 128 * 2);
    __hip_bfloat16* Hr    = (__hip_bfloat16*)alloc((size_t)N_PAPER * 128 * 2);
    unsigned* ebuf_c = (unsigned*)alloc((size_t)E_CITES * 4);
    int*      col_c  = (int*)alloc((size_t)E_CITES * 4);
    unsigned* ebuf_r = (unsigned*)alloc((size_t)E_IS * 4);
    int*      col_r  = (int*)alloc((size_t)E_IS * 4);
    unsigned* ebuf_l = (unsigned*)alloc((size_t)E_IS * 4);
    int*   rp_c  = (int*)alloc((size_t)(N_PAPER + 1) * 4);
    int*   rp_r  = (int*)alloc((size_t)(N_PAPER + 1) * 4);
    int*   rp_l  = (int*)alloc((size_t)(N_LABEL + 1) * 4);
    // contiguous histogram block (one memset): bhist_c(98) bhist_r(98) bhist_l(128)
    int*   bhist_c = (int*)alloc((size_t)(NBKT + NBKT + 128) * 4);
    int*   bhist_r = bhist_c + NBKT;
    int*   bhist_l = bhist_r + NBKT;
    int*   bbase_c = (int*)alloc((size_t)(NBKT + 1) * 4);
    int*   bcur_c  = (int*)alloc((size_t)NBKT * 4);
    int*   bbase_r = (int*)alloc((size_t)(NBKT + 1) * 4);
    int*   bcur_r  = (int*)alloc((size_t)NBKT * 4);
    int*   bcur_l  = (int*)alloc((size_t)128 * 4);
    float* dinv  = (float*)alloc((size_t)N_PAPER * 4);
    __hip_bfloat16* Wp1 = (__hip_bfloat16*)alloc((size_t)32768 * 2);
    __hip_bfloat16* Wp2 = (__hip_bfloat16*)alloc((size_t)16384 * 2);
    float* yrev1 = (float*)alloc(128 * 128 * 4);
    float* yrev2 = (float*)alloc(128 * 64 * 4);
    float* hl1   = (float*)alloc(128 * 128 * 4);
    float* partialL = (float*)alloc((size_t)N_LABEL * LSPLIT * 128 * 4);

    float* zp = (float*)d_out;                          // [100000 x 64]
    float* zl = (float*)d_out + (size_t)N_PAPER * 64;   // [128 x 64]

    hipMemsetAsync(bhist_c, 0, (size_t)(NBKT + NBKT + 128) * 4, stream);

    // ---- CSR builds (cites by dst, rev-is by paper src, is by label dst) ----
    bucket_count_k<NBKT, 10><<<256, 256, 0, stream>>>(cd, E_CITES, bhist_c);
    bucket_count_k<NBKT, 10><<<64, 256, 0, stream>>>(iss, E_IS, bhist_r);
    bucket_count_k<128, 0><<<64, 256, 0, stream>>>(isd, E_IS, bhist_l);
    scan_sums<<<1, 128, 0, stream>>>(bhist_c, bbase_c, bcur_c,
                                     bhist_r, bbase_r, bcur_r,
                                     bhist_l, rp_l, bcur_l);
    bucket_scatter_k<NBKT, 10><<<(E_CITES + A2_CHUNK - 1) / A2_CHUNK, 256, 0, stream>>>(
        cd, cs, E_CITES, bcur_c, ebuf_c);
    bucket_scatter_k<NBKT, 10><<<(E_IS + A2_CHUNK - 1) / A2_CHUNK, 256, 0, stream>>>(
        iss, isd, E_IS, bcur_r, ebuf_r);
    bucket_scatter_k<128, 0><<<(E_IS + A2_CHUNK - 1) / A2_CHUNK, 256, 0, stream>>>(
        isd, iss, E_IS, bcur_l, ebuf_l);
    bucket_csr<true><<<NBKT, 1024, 0, stream>>>(ebuf_c, bbase_c, rp_c, col_c, dinv);
    bucket_csr<false><<<NBKT, 1024, 0, stream>>>(ebuf_r, bbase_r, rp_r, col_r, nullptr);

    conv_bf16<<<(N_PAPER * 128 / 4 + 255) / 256, 256, 0, stream>>>(xp, xp_bf, N_PAPER * 128 / 4);
    pack_wp<<<(32768 + 255) / 256, 256, 0, stream>>>(l1_gcn_W, l1_rev_rootW, Wp1, 128);
    pack_wp<<<(16384 + 255) / 256, 256, 0, stream>>>(l2_gcn_W, l2_rev_rootW, Wp2, 64);
    small_mm<<<128, 128, 0, stream>>>(xl, l1_rev_relW, yrev1, 128);

    // ---- layer 1 ----
    gemm_mfma<128><<<(N_PAPER + 63) / 64, 256, 0, stream>>>(xp_bf, Wp1, dinv, Hg, Hr, N_PAPER);
    paper_assemble<128, true, __hip_bfloat16><<<(N_PAPER + 3) / 4, 256, 0, stream>>>(
        Hg, Hr, rp_c, col_c, dinv, rp_r, col_r, yrev1, l1_gcn_b, l1_rev_relb, hp1);
    label_agg<<<dim3(N_LABEL, LSPLIT), 128, 0, stream>>>(xp_bf, rp_l, ebuf_l, partialL);
    label_finish<128, true><<<N_LABEL, 128, 0, stream>>>(
        partialL, xl, l1_is_relW, l1_is_rootW, l1_is_relb, hl1);
    small_mm<<<128, 128, 0, stream>>>(hl1, l2_rev_relW, yrev2, 64);

    // ---- layer 2 ----
    gemm_mfma<64><<<(N_PAPER + 63) / 64, 256, 0, stream>>>(hp1, Wp2, dinv, Hg, Hr, N_PAPER);
    paper_assemble<64, false, float><<<(N_PAPER + 3) / 4, 256, 0, stream>>>(
        Hg, Hr, rp_c, col_c, dinv, rp_r, col_r, yrev2, l2_gcn_b, l2_rev_relb, zp);
    label_agg<<<dim3(N_LABEL, LSPLIT), 128, 0, stream>>>(hp1, rp_l, ebuf_l, partialL);
    label_finish<64, false><<<N_LABEL, 128, 0, stream>>>(
        partialL, hl1, l2_is_relW, l2_is_rootW, l2_is_relb, zl);
}

// Round 7
// 363.895 us; speedup vs baseline: 4.7962x; 1.1412x over previous
//
#include <hip/hip_runtime.h>
#include <hip/hip_bf16.h>

#define N_PAPER 100000
#define N_LABEL 128
#define E_CITES 1600000
#define E_IS    100000
#define NBKT    98   // node>>10 buckets
#define A2_CHUNK 2048
#define LSPLIT  8

typedef __bf16 bf16x8 __attribute__((ext_vector_type(8)));
typedef float  f32x4  __attribute__((ext_vector_type(4)));

static __device__ __forceinline__ float bf_lo(unsigned u) {
    union { unsigned u; float f; } v; v.u = u << 16; return v.f;
}
static __device__ __forceinline__ float bf_hi(unsigned u) {
    union { unsigned u; float f; } v; v.u = u & 0xffff0000u; return v.f;
}
static __device__ __forceinline__ unsigned pk_bf(float a, float b) {
    __hip_bfloat16 x = __float2bfloat16(a), y = __float2bfloat16(b);
    unsigned short ux = *(unsigned short*)&x, uy = *(unsigned short*)&y;
    return (unsigned)ux | ((unsigned)uy << 16);
}

// ---------------- fused bucket histograms (cites, rev, label) ----------------
#define NCC 224
#define NCR 32
#define NCL 32
__global__ __launch_bounds__(256) void fused_count(
    const int* __restrict__ cd, const int* __restrict__ iss, const int* __restrict__ isd,
    int* __restrict__ bhist_c, int* __restrict__ bhist_r, int* __restrict__ bhist_l)
{
    __shared__ int h[128];
    int b = blockIdx.x, t = threadIdx.x;
    const int* key; int E, shift, nb, b0, nblk; int* hist;
    if (b < NCC)            { key = cd;  E = E_CITES; hist = bhist_c; shift = 10; nb = NBKT; b0 = b;             nblk = NCC; }
    else if (b < NCC + NCR) { key = iss; E = E_IS;    hist = bhist_r; shift = 10; nb = NBKT; b0 = b - NCC;       nblk = NCR; }
    else                    { key = isd; E = E_IS;    hist = bhist_l; shift = 0;  nb = 128;  b0 = b - NCC - NCR; nblk = NCL; }
    if (t < nb) h[t] = 0;
    __syncthreads();
    for (int i = b0 * 256 + t; i < E; i += nblk * 256)
        atomicAdd(&h[key[i] >> shift], 1);
    __syncthreads();
    if (t < nb && h[t]) atomicAdd(&hist[t], h[t]);
}

// single block: exclusive-scan three histograms (cites 98, rev 98, label 128)
__global__ __launch_bounds__(128) void scan_sums(
    const int* __restrict__ bhist_c, int* __restrict__ bbase_c, int* __restrict__ bcur_c,
    const int* __restrict__ bhist_r, int* __restrict__ bbase_r, int* __restrict__ bcur_r,
    const int* __restrict__ bhist_l, int* __restrict__ rp_l, int* __restrict__ bcur_l)
{
    __shared__ int sh[3][128];
    int t = threadIdx.x;
    sh[0][t] = (t < NBKT) ? bhist_c[t] : 0;
    sh[1][t] = (t < NBKT) ? bhist_r[t] : 0;
    sh[2][t] = bhist_l[t];
    __syncthreads();
    for (int off = 1; off < 128; off <<= 1) {
        int v0 = (t >= off) ? sh[0][t - off] : 0;
        int v1 = (t >= off) ? sh[1][t - off] : 0;
        int v2 = (t >= off) ? sh[2][t - off] : 0;
        __syncthreads();
        sh[0][t] += v0; sh[1][t] += v1; sh[2][t] += v2;
        __syncthreads();
    }
    if (t < NBKT) {
        int b = (t == 0) ? 0 : sh[0][t - 1];
        bbase_c[t] = b; bcur_c[t] = b;
        if (t == NBKT - 1) bbase_c[NBKT] = sh[0][t];
        int b2 = (t == 0) ? 0 : sh[1][t - 1];
        bbase_r[t] = b2; bcur_r[t] = b2;
        if (t == NBKT - 1) bbase_r[NBKT] = sh[1][t];
    }
    int b3 = (t == 0) ? 0 : sh[2][t - 1];
    rp_l[t] = b3; bcur_l[t] = b3;
    if (t == 127) rp_l[128] = sh[2][127];
}

// ---------------- fused bucketed edge scatter (packed u32) ----------------
// ebuf[p] = ((key & 1023) << 17) | val   (val < 2^17)
#define NSC ((E_CITES + A2_CHUNK - 1) / A2_CHUNK)
#define NSI ((E_IS + A2_CHUNK - 1) / A2_CHUNK)
__global__ __launch_bounds__(256) void fused_scatter(
    const int* __restrict__ cd, const int* __restrict__ cs,
    const int* __restrict__ iss, const int* __restrict__ isd,
    int* __restrict__ bcur_c, unsigned* __restrict__ ebuf_c,
    int* __restrict__ bcur_r, unsigned* __restrict__ ebuf_r,
    int* __restrict__ bcur_l, unsigned* __restrict__ ebuf_l)
{
    __shared__ int sk[A2_CHUNK], sv[A2_CHUNK];
    __shared__ int h[128], base[128], cur[128];
    int b = blockIdx.x, t = threadIdx.x;
    const int* key; const int* val; int E, shift, b0; int* bcur; unsigned* ebuf;
    if (b < NSC)            { key = cd;  val = cs;  E = E_CITES; bcur = bcur_c; ebuf = ebuf_c; shift = 10; b0 = b; }
    else if (b < NSC + NSI) { key = iss; val = isd; E = E_IS;    bcur = bcur_r; ebuf = ebuf_r; shift = 10; b0 = b - NSC; }
    else                    { key = isd; val = iss; E = E_IS;    bcur = bcur_l; ebuf = ebuf_l; shift = 0;  b0 = b - NSC - NSI; }
    int e0 = b0 * A2_CHUNK;
    int n = min(A2_CHUNK, E - e0);
    for (int i = t; i < 128; i += 256) h[i] = 0;
    __syncthreads();
    for (int i = t; i < n; i += 256) {
        int k = key[e0 + i], v = val[e0 + i];
        sk[i] = k; sv[i] = v;
        atomicAdd(&h[k >> shift], 1);
    }
    __syncthreads();
    for (int i = t; i < 128; i += 256) { base[i] = atomicAdd(&bcur[i], h[i]); cur[i] = 0; }
    __syncthreads();
    for (int i = t; i < n; i += 256) {
        int bb = sk[i] >> shift;
        int p = base[bb] + atomicAdd(&cur[bb], 1);
        ebuf[p] = ((unsigned)(sk[i] & 1023) << 17) | (unsigned)sv[i];
    }
}

// ---------------- fused per-bucket CSR build (cites + rev) ----------------
__global__ __launch_bounds__(1024) void fused_csr(
    const unsigned* __restrict__ ebuf_c, const int* __restrict__ bbase_c,
    int* __restrict__ rp_c, int* __restrict__ col_c, float* __restrict__ dinv,
    const unsigned* __restrict__ ebuf_r, const int* __restrict__ bbase_r,
    int* __restrict__ rp_r, int* __restrict__ col_r)
{
    __shared__ int hist[1024];
    __shared__ int sc[1024];
    int bb = blockIdx.x, t = threadIdx.x;
    const unsigned* ebuf; const int* bbase; int* rp; int* col; float* dv; int b;
    if (bb < NBKT) { ebuf = ebuf_c; bbase = bbase_c; rp = rp_c; col = col_c; dv = dinv; b = bb; }
    else           { ebuf = ebuf_r; bbase = bbase_r; rp = rp_r; col = col_r; dv = nullptr; b = bb - NBKT; }
    int s = bbase[b], e = bbase[b + 1];
    hist[t] = 0;
    __syncthreads();
    for (int i = s + t; i < e; i += 1024)
        atomicAdd(&hist[ebuf[i] >> 17], 1);
    __syncthreads();
    int v = hist[t];
    sc[t] = v;
    __syncthreads();
    for (int off = 1; off < 1024; off <<= 1) {
        int u = (t >= off) ? sc[t - off] : 0;
        __syncthreads();
        sc[t] += u;
        __syncthreads();
    }
    int excl = sc[t] - v;
    int node = b * 1024 + t;
    if (node < N_PAPER) {
        rp[node] = s + excl;
        if (dv) dv[node] = rsqrtf((float)v + 1.0f);
        if (node == N_PAPER - 1) rp[N_PAPER] = s + excl + v;
    }
    __syncthreads();
    hist[t] = s + excl;   // reuse as running cursor
    __syncthreads();
    for (int i = s + t; i < e; i += 1024) {
        unsigned u = ebuf[i];
        int p = atomicAdd(&hist[u >> 17], 1);
        col[p] = (int)(u & 0x1FFFFu);
    }
}

// ---------------- fused prep: conv_bf16 + pack_wp(1,2) + yrev1 small_mm -----
#define NCONV 12500   // 100000*128/4 / 256
__global__ __launch_bounds__(256) void fused_prep(
    const float* __restrict__ xp, __hip_bfloat16* __restrict__ xp_bf,
    const float* __restrict__ g1, const float* __restrict__ r1, __hip_bfloat16* __restrict__ Wp1,
    const float* __restrict__ g2, const float* __restrict__ r2, __hip_bfloat16* __restrict__ Wp2,
    const float* __restrict__ xl, const float* __restrict__ W1rev, float* __restrict__ yrev1)
{
    int b = blockIdx.x, t = threadIdx.x;
    if (b < NCONV) {
        int i = b * 256 + t;
        const int n4 = N_PAPER * 128 / 4;
        if (i < n4) {
            float4 v = *(const float4*)(xp + (size_t)i * 4);
            __hip_bfloat16* o = xp_bf + (size_t)i * 4;
            o[0] = __float2bfloat16(v.x); o[1] = __float2bfloat16(v.y);
            o[2] = __float2bfloat16(v.z); o[3] = __float2bfloat16(v.w);
        }
        return;
    }
    if (b < NCONV + 128 + 64) {
        // pack Wp: b-NCONV<128 -> DG=128, else DG=64
        bool big = (b < NCONV + 128);
        const float* g = big ? g1 : g2;
        const float* r = big ? r1 : r2;
        __hip_bfloat16* Wp = big ? Wp1 : Wp2;
        int DG = big ? 128 : 64;
        int i = (big ? (b - NCONV) : (b - NCONV - 128)) * 256 + t;
        int j    = i & 7;
        int lane = (i >> 3) & 63;
        int ks   = (i >> 9) & 3;
        int nt   = i >> 11;
        int k = ks * 32 + (lane >> 4) * 8 + j;
        int c = nt * 16 + (lane & 15);
        float v = (c < DG) ? g[k * DG + c] : r[k * DG + (c - DG)];
        Wp[i] = __float2bfloat16(v);
        return;
    }
    // yrev1: 64 blocks, 2 labels per block
    __shared__ float xrow[2][128];
    int bb = b - (NCONV + 128 + 64);
    int half = t >> 7, tt = t & 127;
    int l = bb * 2 + half;
    xrow[half][tt] = xl[(size_t)l * 128 + tt];
    __syncthreads();
    float o = 0.f;
    for (int k = 0; k < 128; ++k) o = fmaf(xrow[half][k], W1rev[k * 128 + tt], o);
    yrev1[(size_t)l * 128 + tt] = o;
}

// ---------------- MFMA GEMM: Hg = dinv.*(A@Wg), Hr = A@Wr  (bf16) ----------
template<int DG>
__global__ __launch_bounds__(256) void gemm_mfma(
    const __hip_bfloat16* __restrict__ A, const __hip_bfloat16* __restrict__ Wp,
    const float* __restrict__ dinv,
    __hip_bfloat16* __restrict__ Hg, __hip_bfloat16* __restrict__ Hr, int M)
{
    constexpr int NT2 = 2 * DG / 16;
    int tid = threadIdx.x;
    int wv = tid >> 6, lane = tid & 63;
    int m0 = blockIdx.x * 64 + wv * 16;
    int row = m0 + (lane & 15);
    int rowc = min(row, M - 1);
    int kg = lane >> 4;

    bf16x8 a[4];
    const __hip_bfloat16* ap = A + (size_t)rowc * 128 + kg * 8;
    #pragma unroll
    for (int ks = 0; ks < 4; ++ks)
        a[ks] = *(const bf16x8*)(ap + ks * 32);

    f32x4 acc[NT2] = {};
    #pragma unroll
    for (int ks = 0; ks < 4; ++ks) {
        #pragma unroll
        for (int nt = 0; nt < NT2; ++nt) {
            bf16x8 b = *(const bf16x8*)(Wp + ((size_t)(nt * 4 + ks) * 64 + lane) * 8);
            acc[nt] = __builtin_amdgcn_mfma_f32_16x16x32_bf16(a[ks], b, acc[nt], 0, 0, 0);
        }
    }

    int rbase = m0 + (lane >> 4) * 4;
    int c = lane & 15;
    float ds[4];
    #pragma unroll
    for (int r = 0; r < 4; ++r) {
        int rr = rbase + r;
        ds[r] = (rr < M) ? dinv[rr] : 1.f;
    }
    #pragma unroll
    for (int nt = 0; nt < NT2; ++nt) {
        bool isG = (nt < DG / 16);
        __hip_bfloat16* dst = isG ? Hg : Hr;
        int cc = isG ? (nt * 16 + c) : ((nt - DG / 16) * 16 + c);
        #pragma unroll
        for (int r = 0; r < 4; ++r) {
            int rr = rbase + r;
            float v = isG ? acc[nt][r] * ds[r] : acc[nt][r];
            if (rr < M) dst[(size_t)rr * DG + cc] = __float2bfloat16(v);
        }
    }
}

// ---------------- fused paper-side assembly (bf16 H, Hg pre-scaled) ---------
// 2-way unrolled edge loop: 8 rows in flight per wave.
template<int D, bool RELU, typename OutT>
__global__ __launch_bounds__(256) void paper_assemble(
    const __hip_bfloat16* __restrict__ Hg, const __hip_bfloat16* __restrict__ Hr,
    const int* __restrict__ rp_c, const int* __restrict__ col_c,
    const float* __restrict__ dinv,
    const int* __restrict__ rp_r, const int* __restrict__ col_r,
    const float* __restrict__ yrev,
    const float* __restrict__ gcn_b, const float* __restrict__ rev_relb,
    OutT* __restrict__ out)
{
    constexpr int NB = D / 16;  // dims per lane: 8 (D=128) or 4 (D=64)
    int w = (int)((blockIdx.x * 256 + threadIdx.x) >> 6);
    if (w >= N_PAPER) return;
    int lane = threadIdx.x & 63;
    int grp = lane >> 4, sub = lane & 15;
    int d0 = sub * NB;
    float acc[NB] = {};
    int s = rp_c[w], e = rp_c[w + 1];
    int j = s + grp;
    for (; j + 4 < e; j += 8) {
        int src0 = col_c[j];
        int src1 = col_c[j + 4];
        const __hip_bfloat16* p0 = Hg + (size_t)src0 * D + d0;
        const __hip_bfloat16* p1 = Hg + (size_t)src1 * D + d0;
        if constexpr (NB == 8) {
            uint4 u = *(const uint4*)p0;
            uint4 v = *(const uint4*)p1;
            acc[0] += bf_lo(u.x) + bf_lo(v.x); acc[1] += bf_hi(u.x) + bf_hi(v.x);
            acc[2] += bf_lo(u.y) + bf_lo(v.y); acc[3] += bf_hi(u.y) + bf_hi(v.y);
            acc[4] += bf_lo(u.z) + bf_lo(v.z); acc[5] += bf_hi(u.z) + bf_hi(v.z);
            acc[6] += bf_lo(u.w) + bf_lo(v.w); acc[7] += bf_hi(u.w) + bf_hi(v.w);
        } else {
            uint2 u = *(const uint2*)p0;
            uint2 v = *(const uint2*)p1;
            acc[0] += bf_lo(u.x) + bf_lo(v.x); acc[1] += bf_hi(u.x) + bf_hi(v.x);
            acc[2] += bf_lo(u.y) + bf_lo(v.y); acc[3] += bf_hi(u.y) + bf_hi(v.y);
        }
    }
    if (j < e) {
        int src = col_c[j];
        const __hip_bfloat16* p = Hg + (size_t)src * D + d0;
        if constexpr (NB == 8) {
            uint4 u = *(const uint4*)p;
            acc[0] += bf_lo(u.x); acc[1] += bf_hi(u.x);
            acc[2] += bf_lo(u.y); acc[3] += bf_hi(u.y);
            acc[4] += bf_lo(u.z); acc[5] += bf_hi(u.z);
            acc[6] += bf_lo(u.w); acc[7] += bf_hi(u.w);
        } else {
            uint2 u = *(const uint2*)p;
            acc[0] += bf_lo(u.x); acc[1] += bf_hi(u.x);
            acc[2] += bf_lo(u.y); acc[3] += bf_hi(u.y);
        }
    }
    #pragma unroll
    for (int k = 0; k < NB; ++k) {
        acc[k] += __shfl_xor(acc[k], 16);
        acc[k] += __shfl_xor(acc[k], 32);
    }
    if (grp != 0) return;

    float di = dinv[w];
    float res[NB];
    const __hip_bfloat16* hg = Hg + (size_t)w * D + d0;
    const __hip_bfloat16* hr = Hr + (size_t)w * D + d0;
    if constexpr (NB == 8) {
        uint4 ug = *(const uint4*)hg;
        uint4 ur = *(const uint4*)hr;
        float sg[8] = { bf_lo(ug.x), bf_hi(ug.x), bf_lo(ug.y), bf_hi(ug.y),
                        bf_lo(ug.z), bf_hi(ug.z), bf_lo(ug.w), bf_hi(ug.w) };
        float sr[8] = { bf_lo(ur.x), bf_hi(ur.x), bf_lo(ur.y), bf_hi(ur.y),
                        bf_lo(ur.z), bf_hi(ur.z), bf_lo(ur.w), bf_hi(ur.w) };
        #pragma unroll
        for (int k = 0; k < 8; ++k)
            res[k] = di * (acc[k] + sg[k]) + sr[k] + gcn_b[d0 + k] + rev_relb[d0 + k];
    } else {
        uint2 ug = *(const uint2*)hg;
        uint2 ur = *(const uint2*)hr;
        float sg[4] = { bf_lo(ug.x), bf_hi(ug.x), bf_lo(ug.y), bf_hi(ug.y) };
        float sr[4] = { bf_lo(ur.x), bf_hi(ur.x), bf_lo(ur.y), bf_hi(ur.y) };
        #pragma unroll
        for (int k = 0; k < 4; ++k)
            res[k] = di * (acc[k] + sg[k]) + sr[k] + gcn_b[d0 + k] + rev_relb[d0 + k];
    }
    int s2 = rp_r[w], e2 = rp_r[w + 1];
    for (int jj = s2; jj < e2; ++jj) {
        const float* yr = yrev + (size_t)col_r[jj] * D + d0;
        #pragma unroll
        for (int k = 0; k < NB; ++k) res[k] += yr[k];
    }
    #pragma unroll
    for (int k = 0; k < NB; ++k) {
        res[k] *= 0.5f;
        if (RELU) res[k] = fmaxf(res[k], 0.f);
    }
    if constexpr (sizeof(OutT) == 2) {
        if constexpr (NB == 8) {
            uint4 o = make_uint4(pk_bf(res[0], res[1]), pk_bf(res[2], res[3]),
                                 pk_bf(res[4], res[5]), pk_bf(res[6], res[7]));
            *(uint4*)(out + (size_t)w * D + d0) = o;
        } else {
            uint2 o = make_uint2(pk_bf(res[0], res[1]), pk_bf(res[2], res[3]));
            *(uint2*)(out + (size_t)w * D + d0) = o;
        }
    } else {
        if constexpr (NB == 8) {
            *(float4*)((float*)out + (size_t)w * D + d0) =
                make_float4(res[0], res[1], res[2], res[3]);
            *(float4*)((float*)out + (size_t)w * D + d0 + 4) =
                make_float4(res[4], res[5], res[6], res[7]);
        } else {
            *(float4*)((float*)out + (size_t)w * D + d0) =
                make_float4(res[0], res[1], res[2], res[3]);
        }
    }
}

// ---------------- label-side aggregation (grid: 128 labels x LSPLIT) --------
__global__ __launch_bounds__(128) void label_agg(
    const __hip_bfloat16* __restrict__ Xsrc,
    const int* __restrict__ rp_l, const unsigned* __restrict__ ebuf_l,
    float* __restrict__ partialL)
{
    int l = blockIdx.x, sp = blockIdx.y, t = threadIdx.x;
    int s = rp_l[l], e = rp_l[l + 1];
    int n = e - s;
    int per = (n + LSPLIT - 1) / LSPLIT;
    int b = s + sp * per;
    int en = min(b + per, e);
    float acc = 0.f;
    for (int m = b; m < en; ++m)
        acc += __bfloat162float(Xsrc[(size_t)(ebuf_l[m] & 0x1FFFFu) * 128 + t]);
    partialL[((size_t)l * LSPLIT + sp) * 128 + t] = acc;
}

// ---------------- label-side finish: sum partials + tiny GEMM (+ yrev2) -----
template<int DOUT, bool RELU, bool YREV2>
__global__ __launch_bounds__(128) void label_finish(
    const float* __restrict__ partialL, const float* __restrict__ Xdst,
    const float* __restrict__ relW, const float* __restrict__ rootW,
    const float* __restrict__ relb, float* __restrict__ out,
    const float* __restrict__ W2rev, float* __restrict__ yrev2)
{
    __shared__ float arow[128];
    __shared__ float xrow[128];
    __shared__ float hrow[128];
    int l = blockIdx.x, t = threadIdx.x;
    float a = 0.f;
    #pragma unroll
    for (int sp = 0; sp < LSPLIT; ++sp)
        a += partialL[((size_t)l * LSPLIT + sp) * 128 + t];
    arow[t] = a;
    xrow[t] = Xdst[(size_t)l * 128 + t];
    __syncthreads();
    float o = 0.f;
    if (t < DOUT) {
        o = relb[t];
        for (int k = 0; k < 128; ++k)
            o = fmaf(arow[k], relW[k * DOUT + t], fmaf(xrow[k], rootW[k * DOUT + t], o));
        if (RELU) o = fmaxf(o, 0.f);
        out[(size_t)l * DOUT + t] = o;
    }
    if constexpr (YREV2) {
        hrow[t] = o;           // DOUT == 128 here
        __syncthreads();
        if (t < 64) {
            float y = 0.f;
            for (int k = 0; k < 128; ++k)
                y = fmaf(hrow[k], W2rev[k * 64 + t], y);
            yrev2[(size_t)l * 64 + t] = y;
        }
    }
}

extern "C" void kernel_launch(void* const* d_in, const int* in_sizes, int n_in,
                              void* d_out, int out_size, void* d_ws, size_t ws_size,
                              hipStream_t stream)
{
    const float* xp          = (const float*)d_in[0];
    const float* xl          = (const float*)d_in[1];
    const int*   cs          = (const int*)d_in[2];
    const int*   cd          = (const int*)d_in[3];
    const int*   iss         = (const int*)d_in[4];
    const int*   isd         = (const int*)d_in[5];
    const float* l1_gcn_W    = (const float*)d_in[6];
    const float* l1_gcn_b    = (const float*)d_in[7];
    const float* l1_is_relW  = (const float*)d_in[8];
    const float* l1_is_relb  = (const float*)d_in[9];
    const float* l1_is_rootW = (const float*)d_in[10];
    const float* l1_rev_relW = (const float*)d_in[11];
    const float* l1_rev_relb = (const float*)d_in[12];
    const float* l1_rev_rootW= (const float*)d_in[13];
    const float* l2_gcn_W    = (const float*)d_in[14];
    const float* l2_gcn_b    = (const float*)d_in[15];
    const float* l2_is_relW  = (const float*)d_in[16];
    const float* l2_is_relb  = (const float*)d_in[17];
    const float* l2_is_rootW = (const float*)d_in[18];
    const float* l2_rev_relW = (const float*)d_in[19];
    const float* l2_rev_relb = (const float*)d_in[20];
    const float* l2_rev_rootW= (const float*)d_in[21];

    char* ws = (char*)d_ws;
    size_t off = 0;
    auto alloc = [&](size_t bytes) {
        char* p = ws + off;
        off += (bytes + 255) & ~(size_t)255;
        return p;
    };
    __hip_bfloat16* xp_bf = (__hip_bfloat16*)alloc((size_t)N_PAPER * 128 * 2);
    __hip_bfloat16* hp1   = (__hip_bfloat16*)alloc((size_t)N_PAPER * 128 * 2);
    __hip_bfloat16* Hg    = (__hip_bfloat16*)alloc((size_t)N_PAPER * 128 * 2);
    __hip_bfloat16* Hr    = (__hip_bfloat16*)alloc((size_t)N_PAPER * 128 * 2);
    unsigned* ebuf_c = (unsigned*)alloc((size_t)E_CITES * 4);
    int*      col_c  = (int*)alloc((size_t)E_CITES * 4);
    unsigned* ebuf_r = (unsigned*)alloc((size_t)E_IS * 4);
    int*      col_r  = (int*)alloc((size_t)E_IS * 4);
    unsigned* ebuf_l = (unsigned*)alloc((size_t)E_IS * 4);
    int*   rp_c  = (int*)alloc((size_t)(N_PAPER + 1) * 4);
    int*   rp_r  = (int*)alloc((size_t)(N_PAPER + 1) * 4);
    int*   rp_l  = (int*)alloc((size_t)(N_LABEL + 1) * 4);
    int*   bhist_c = (int*)alloc((size_t)(NBKT + NBKT + 128) * 4);
    int*   bhist_r = bhist_c + NBKT;
    int*   bhist_l = bhist_r + NBKT;
    int*   bbase_c = (int*)alloc((size_t)(NBKT + 1) * 4);
    int*   bcur_c  = (int*)alloc((size_t)NBKT * 4);
    int*   bbase_r = (int*)alloc((size_t)(NBKT + 1) * 4);
    int*   bcur_r  = (int*)alloc((size_t)NBKT * 4);
    int*   bcur_l  = (int*)alloc((size_t)128 * 4);
    float* dinv  = (float*)alloc((size_t)N_PAPER * 4);
    __hip_bfloat16* Wp1 = (__hip_bfloat16*)alloc((size_t)32768 * 2);
    __hip_bfloat16* Wp2 = (__hip_bfloat16*)alloc((size_t)16384 * 2);
    float* yrev1 = (float*)alloc(128 * 128 * 4);
    float* yrev2 = (float*)alloc(128 * 64 * 4);
    float* hl1   = (float*)alloc(128 * 128 * 4);
    float* partialL = (float*)alloc((size_t)N_LABEL * LSPLIT * 128 * 4);

    float* zp = (float*)d_out;                          // [100000 x 64]
    float* zl = (float*)d_out + (size_t)N_PAPER * 64;   // [128 x 64]

    hipMemsetAsync(bhist_c, 0, (size_t)(NBKT + NBKT + 128) * 4, stream);

    // ---- CSR builds (cites by dst, rev-is by paper src, is by label dst) ----
    fused_count<<<NCC + NCR + NCL, 256, 0, stream>>>(cd, iss, isd, bhist_c, bhist_r, bhist_l);
    scan_sums<<<1, 128, 0, stream>>>(bhist_c, bbase_c, bcur_c,
                                     bhist_r, bbase_r, bcur_r,
                                     bhist_l, rp_l, bcur_l);
    fused_scatter<<<NSC + 2 * NSI, 256, 0, stream>>>(cd, cs, iss, isd,
                                                     bcur_c, ebuf_c, bcur_r, ebuf_r, bcur_l, ebuf_l);
    fused_csr<<<2 * NBKT, 1024, 0, stream>>>(ebuf_c, bbase_c, rp_c, col_c, dinv,
                                             ebuf_r, bbase_r, rp_r, col_r);
    fused_prep<<<NCONV + 128 + 64 + 64, 256, 0, stream>>>(
        xp, xp_bf, l1_gcn_W, l1_rev_rootW, Wp1, l2_gcn_W, l2_rev_rootW, Wp2,
        xl, l1_rev_relW, yrev1);

    // ---- layer 1 ----
    gemm_mfma<128><<<(N_PAPER + 63) / 64, 256, 0, stream>>>(xp_bf, Wp1, dinv, Hg, Hr, N_PAPER);
    paper_assemble<128, true, __hip_bfloat16><<<(N_PAPER + 3) / 4, 256, 0, stream>>>(
        Hg, Hr, rp_c, col_c, dinv, rp_r, col_r, yrev1, l1_gcn_b, l1_rev_relb, hp1);
    label_agg<<<dim3(N_LABEL, LSPLIT), 128, 0, stream>>>(xp_bf, rp_l, ebuf_l, partialL);
    label_finish<128, true, true><<<N_LABEL, 128, 0, stream>>>(
        partialL, xl, l1_is_relW, l1_is_rootW, l1_is_relb, hl1, l2_rev_relW, yrev2);

    // ---- layer 2 ----
    gemm_mfma<64><<<(N_PAPER + 63) / 64, 256, 0, stream>>>(hp1, Wp2, dinv, Hg, Hr, N_PAPER);
    paper_assemble<64, false, float><<<(N_PAPER + 3) / 4, 256, 0, stream>>>(
        Hg, Hr, rp_c, col_c, dinv, rp_r, col_r, yrev2, l2_gcn_b, l2_rev_relb, zp);
    label_agg<<<dim3(N_LABEL, LSPLIT), 128, 0, stream>>>(hp1, rp_l, ebuf_l, partialL);
    label_finish<64, false, false><<<N_LABEL, 128, 0, stream>>>(
        partialL, hl1, l2_is_relW, l2_is_rootW, l2_is_relb, zl, nullptr, nullptr);
}